// Round 6
// baseline (1390.233 us; speedup 1.0000x reference)
//
#include <hip/hip_runtime.h>
#include <math.h>

#define Bb 16
#define Nn 500
#define NT 501
#define Pp 100
#define Ee 128
#define Hh 8
#define Dd 16
#define Ff 512
#define Ll 6
#define Mtok (Bb*NT)   // 8016
#define PR (Bb*Pp)     // 1600
#define TJ 32          // attn_enc KV tile rows
#define ENCP (6*128*384)
#define DECP (128*256)

// ---------------------------------------------------------------- weight packing
// encP[l][k][n] : n<128 wq | n<256 wk | n<384 wv ;  decP[k][n]: n<128 wk | wv
__global__ __launch_bounds__(256) void pack_k(
    const float* __restrict__ ewq, const float* __restrict__ ewk, const float* __restrict__ ewv,
    const float* __restrict__ dwk, const float* __restrict__ dwv,
    float* __restrict__ encP, float* __restrict__ decP)
{
  int i = blockIdx.x*256 + threadIdx.x;
  if (i < ENCP) {
    int l = i / (128*384); int rem = i - l*128*384; int k = rem / 384; int n = rem - k*384;
    float v;
    if (n < 128)      v = ewq[((size_t)l*128 + k)*128 + n];
    else if (n < 256) v = ewk[((size_t)l*128 + k)*128 + (n-128)];
    else              v = ewv[((size_t)l*128 + k)*128 + (n-256)];
    encP[i] = v;
  } else {
    int j = i - ENCP;
    if (j < DECP) {
      int k = j >> 8; int n = j & 255;
      decP[j] = (n < 128) ? dwk[k*128 + n] : dwv[k*128 + (n-128)];
    }
  }
}

// ---------------------------------------------------------------- embed
__global__ __launch_bounds__(256) void embed_k(
    const float* __restrict__ depot_xy, const float* __restrict__ node_xy,
    const float* __restrict__ node_demand,
    const float* __restrict__ wD, const float* __restrict__ bD,
    const float* __restrict__ wN, const float* __restrict__ bN,
    float* __restrict__ x)
{
  int t = blockIdx.x*256 + threadIdx.x;
  if (t >= Mtok*Ee) return;
  int e   = t & (Ee-1);
  int tok = t >> 7;
  int b   = tok / NT;
  int n   = tok - b*NT;
  float v;
  if (n == 0) {
    v = depot_xy[b*2+0]*wD[0*Ee+e] + depot_xy[b*2+1]*wD[1*Ee+e] + bD[e];
  } else {
    int nn = n - 1;
    float c0 = node_xy[(b*Nn + nn)*2 + 0];
    float c1 = node_xy[(b*Nn + nn)*2 + 1];
    float c2 = node_demand[b*Nn + nn];
    v = c0*wN[0*Ee+e] + c1*wN[1*Ee+e] + c2*wN[2*Ee+e] + bN[e];
  }
  x[(size_t)tok*Ee + e] = v;
}

// ---------------------------------------------------------------- GEMM
// C[M,N] = A[M,K] @ W[K,N]  (+bias) (relu) (+res).  N%64==0, K%16==0.
__global__ __launch_bounds__(256) void gemm_k(
    const float* __restrict__ A, const float* __restrict__ W,
    const float* __restrict__ bias, const float* __restrict__ res,
    float* __restrict__ C, int M, int N, int K, int relu)
{
  __shared__ __align__(16) float As[16][64];
  __shared__ __align__(16) float Bs[16][64];
  int tid = threadIdx.x;
  int tx = tid & 15, ty = tid >> 4;
  int m0 = blockIdx.x * 64, n0 = blockIdx.y * 64;
  float acc[4][4];
  #pragma unroll
  for (int i=0;i<4;i++)
    #pragma unroll
    for (int j=0;j<4;j++) acc[i][j] = 0.f;

  int ar = tid >> 2;          // 0..63  A row in tile
  int ak = (tid & 3) << 2;    // 0,4,8,12
  int br = tid >> 4;          // 0..15  W row in tile
  int bc = (tid & 15) << 2;   // 0..60

  const float* Ap = A + (size_t)(m0 + ar)*K + ak;
  const float* Wp = W + (size_t)br*N + n0 + bc;
  bool aok = (m0 + ar) < M;

  float4 av = aok ? *(const float4*)(Ap) : make_float4(0.f,0.f,0.f,0.f);
  float4 wv = *(const float4*)(Wp);

  for (int k0 = 0; k0 < K; k0 += 16) {
    As[ak+0][ar] = av.x; As[ak+1][ar] = av.y; As[ak+2][ar] = av.z; As[ak+3][ar] = av.w;
    *(float4*)(&Bs[br][bc]) = wv;
    __syncthreads();
    if (k0 + 16 < K) {
      av = aok ? *(const float4*)(Ap + k0 + 16) : make_float4(0.f,0.f,0.f,0.f);
      wv = *(const float4*)(Wp + (size_t)(k0 + 16)*N);
    }
    #pragma unroll
    for (int k=0;k<16;k++){
      float4 a4 = *(const float4*)(&As[k][ty*4]);
      float4 b4 = *(const float4*)(&Bs[k][tx*4]);
      float avv[4] = {a4.x,a4.y,a4.z,a4.w};
      float bvv[4] = {b4.x,b4.y,b4.z,b4.w};
      #pragma unroll
      for (int i=0;i<4;i++)
        #pragma unroll
        for (int j=0;j<4;j++)
          acc[i][j] = fmaf(avv[i], bvv[j], acc[i][j]);
    }
    __syncthreads();
  }

  float4 bv = make_float4(0.f,0.f,0.f,0.f);
  if (bias) bv = *(const float4*)(bias + n0 + tx*4);
  #pragma unroll
  for (int i=0;i<4;i++){
    int row = m0 + ty*4 + i;
    if (row >= M) continue;
    float4 o;
    o.x = acc[i][0] + bv.x; o.y = acc[i][1] + bv.y;
    o.z = acc[i][2] + bv.z; o.w = acc[i][3] + bv.w;
    if (relu){ o.x=fmaxf(o.x,0.f); o.y=fmaxf(o.y,0.f); o.z=fmaxf(o.z,0.f); o.w=fmaxf(o.w,0.f); }
    if (res){
      float4 rv = *(const float4*)(res + (size_t)row*N + n0 + tx*4);
      o.x += rv.x; o.y += rv.y; o.z += rv.z; o.w += rv.w;
    }
    *(float4*)(C + (size_t)row*N + n0 + tx*4) = o;
  }
}

// ---------------------------------------------------------------- attention
__device__ __forceinline__ float dot4(float4 a, float4 b){
  return fmaf(a.x,b.x, fmaf(a.y,b.y, fmaf(a.z,b.z, a.w*b.w)));
}

// encoder self-attention over fused QKV buffer [Mtok][384] (Q|K|V each 128).
// one (b,h,chunk) per block, one query per thread; K/V tiles double-buffered
// in LDS (broadcast reads); defer-max cheap path (T13).
__global__ __launch_bounds__(256) void attn_enc_k(
    const float* __restrict__ QKV, float* __restrict__ O)
{
  int blk = blockIdx.x;            // ((b*H)+h)*2 + c
  int c  = blk & 1;
  int bh = blk >> 1;
  int h  = bh & (Hh-1);
  int b  = bh >> 3;
  int p  = c*256 + (int)threadIdx.x;

  __shared__ __align__(16) float4 Ks[2][TJ][4];
  __shared__ __align__(16) float4 Vs[2][TJ][4];

  int tid = threadIdx.x;
  int row = (tid >> 2) & 31;        // 0..31
  int lc  = tid & 3;                // float4 quad within row
  bool isV = tid >= 128;
  const int kvoff = isV ? 256 : 128;

  float4 q0,q1,q2,q3;
  if (p < NT) {
    const float4* qp = (const float4*)(QKV + ((size_t)(b*NT + p))*384 + h*Dd);
    q0=qp[0]; q1=qp[1]; q2=qp[2]; q3=qp[3];
  } else {
    q0=q1=q2=q3=make_float4(0,0,0,0);
  }

  // load tile 0
  if (row < NT) {
    float4 v = *((const float4*)(QKV + ((size_t)(b*NT + row))*384 + kvoff + h*Dd) + lc);
    if (isV) Vs[0][row][lc] = v; else Ks[0][row][lc] = v;
  }
  __syncthreads();

  float m = -1e30f, l = 0.f;
  float4 o0=make_float4(0,0,0,0), o1=o0, o2=o0, o3=o0;
  const int ntiles = (NT + TJ - 1)/TJ;   // 16
  int buf = 0;

  for (int t = 0; t < ntiles; ++t) {
    int j0 = t*TJ;
    if (t+1 < ntiles) {
      int jj = j0 + TJ + row;
      if (jj < NT) {
        float4 v = *((const float4*)(QKV + ((size_t)(b*NT + jj))*384 + kvoff + h*Dd) + lc);
        if (isV) Vs[buf^1][row][lc] = v; else Ks[buf^1][row][lc] = v;
      }
    }
    int jend = NT - j0; if (jend > TJ) jend = TJ;

    if (p < NT) {
      #pragma unroll 4
      for (int jj=0;jj<jend;jj++){
        const float4* kr = &Ks[buf][jj][0];
        float s = (dot4(q0,kr[0])+dot4(q1,kr[1])) + (dot4(q2,kr[2])+dot4(q3,kr[3]));
        s *= 0.25f;
        const float4* vr = &Vs[buf][jj][0];
        float4 v0=vr[0],v1=vr[1],v2=vr[2],v3=vr[3];
        if (__any(s > m + 8.0f)) {
          float mn = fmaxf(m, s);
          float cf = __expf(m - mn);
          float w  = __expf(s - mn);
          l = l*cf + w;
          o0.x=fmaf(w,v0.x,o0.x*cf); o0.y=fmaf(w,v0.y,o0.y*cf); o0.z=fmaf(w,v0.z,o0.z*cf); o0.w=fmaf(w,v0.w,o0.w*cf);
          o1.x=fmaf(w,v1.x,o1.x*cf); o1.y=fmaf(w,v1.y,o1.y*cf); o1.z=fmaf(w,v1.z,o1.z*cf); o1.w=fmaf(w,v1.w,o1.w*cf);
          o2.x=fmaf(w,v2.x,o2.x*cf); o2.y=fmaf(w,v2.y,o2.y*cf); o2.z=fmaf(w,v2.z,o2.z*cf); o2.w=fmaf(w,v2.w,o2.w*cf);
          o3.x=fmaf(w,v3.x,o3.x*cf); o3.y=fmaf(w,v3.y,o3.y*cf); o3.z=fmaf(w,v3.z,o3.z*cf); o3.w=fmaf(w,v3.w,o3.w*cf);
          m = mn;
        } else {
          float w = __expf(s - m);
          l += w;
          o0.x=fmaf(w,v0.x,o0.x); o0.y=fmaf(w,v0.y,o0.y); o0.z=fmaf(w,v0.z,o0.z); o0.w=fmaf(w,v0.w,o0.w);
          o1.x=fmaf(w,v1.x,o1.x); o1.y=fmaf(w,v1.y,o1.y); o1.z=fmaf(w,v1.z,o1.z); o1.w=fmaf(w,v1.w,o1.w);
          o2.x=fmaf(w,v2.x,o2.x); o2.y=fmaf(w,v2.y,o2.y); o2.z=fmaf(w,v2.z,o2.z); o2.w=fmaf(w,v2.w,o2.w);
          o3.x=fmaf(w,v3.x,o3.x); o3.y=fmaf(w,v3.y,o3.y); o3.z=fmaf(w,v3.z,o3.z); o3.w=fmaf(w,v3.w,o3.w);
        }
      }
    }
    __syncthreads();
    buf ^= 1;
  }

  if (p < NT) {
    float inv = 1.0f/l;
    float4* op = (float4*)(O + ((size_t)(b*NT + p))*Ee + h*Dd);
    op[0] = make_float4(o0.x*inv,o0.y*inv,o0.z*inv,o0.w*inv);
    op[1] = make_float4(o1.x*inv,o1.y*inv,o1.z*inv,o1.w*inv);
    op[2] = make_float4(o2.x*inv,o2.y*inv,o2.z*inv,o2.w*inv);
    op[3] = make_float4(o3.x*inv,o3.y*inv,o3.z*inv,o3.w*inv);
  }
}

// decoder cross-attention over fused KV buffer [Mtok][256] (K|V).
// one block per (b,p); thread = (h, j-lane): in-register D=16 dot, no in-loop
// shuffles; 16-lane online-softmax merge at the end.
__global__ __launch_bounds__(128) void attn_dec_k(
    const float* __restrict__ Q, const float* __restrict__ KV,
    const float* __restrict__ mask, float* __restrict__ O)
{
  int r = blockIdx.x;              // b*Pp + p
  int b = r / Pp;
  int t = threadIdx.x;
  int h = t >> 4;
  int ln = t & 15;                 // j-lane within head group
  const float4* qp = (const float4*)(Q + (size_t)r*Ee + h*Dd);
  float4 qa=qp[0], qb=qp[1], qc=qp[2], qd=qp[3];
  const float* kvb = KV + ((size_t)(b*NT))*256;
  const float* mrow = mask + (size_t)r*NT;

  float m = -1e30f, l = 0.f;
  float o[16];
  #pragma unroll
  for (int d=0; d<16; ++d) o[d] = 0.f;

  for (int j = ln; j < NT; j += 16) {
    const float4* kr = (const float4*)(kvb + (size_t)j*256 + h*Dd);
    float4 k0=kr[0],k1=kr[1],k2=kr[2],k3=kr[3];
    float s = (dot4(qa,k0)+dot4(qb,k1)) + (dot4(qc,k2)+dot4(qd,k3));
    s = s*0.25f + mrow[j];
    const float4* vr = (const float4*)(kvb + (size_t)j*256 + 128 + h*Dd);
    float4 v0=vr[0],v1=vr[1],v2=vr[2],v3=vr[3];
    float vv[16] = {v0.x,v0.y,v0.z,v0.w, v1.x,v1.y,v1.z,v1.w,
                    v2.x,v2.y,v2.z,v2.w, v3.x,v3.y,v3.z,v3.w};
    if (__any(s > m + 8.0f)) {
      float mn = fmaxf(m, s);
      float cf = __expf(m - mn);
      float w  = __expf(s - mn);
      l = l*cf + w;
      #pragma unroll
      for (int d=0; d<16; ++d) o[d] = fmaf(w, vv[d], o[d]*cf);
      m = mn;
    } else {
      float w = __expf(s - m);
      l += w;
      #pragma unroll
      for (int d=0; d<16; ++d) o[d] = fmaf(w, vv[d], o[d]);
    }
  }

  // merge the 16 j-lane partials (butterfly within 16-lane groups)
  #pragma unroll
  for (int off=8; off>=1; off>>=1) {
    float m2 = __shfl_xor(m, off, 16);
    float l2 = __shfl_xor(l, off, 16);
    float mn = fmaxf(m, m2);
    float c1 = __expf(m - mn);
    float c2 = __expf(m2 - mn);
    l = l*c1 + l2*c2;
    #pragma unroll
    for (int d=0; d<16; ++d) {
      float od = __shfl_xor(o[d], off, 16);
      o[d] = o[d]*c1 + od*c2;
    }
    m = mn;
  }
  // lane ln writes element ln (static-index select, no scratch)
  float outv = 0.f;
  #pragma unroll
  for (int d=0; d<16; ++d) outv = (ln == d) ? o[d] : outv;
  O[(size_t)r*Ee + h*Dd + ln] = outv / l;
}

// ---------------------------------------------------------------- decoder small ops
__global__ __launch_bounds__(256) void gather_k(
    const float* __restrict__ x, const int* __restrict__ cur, float* __restrict__ encl)
{
  int t = blockIdx.x*256 + threadIdx.x;
  if (t >= PR*Ee) return;
  int e = t & (Ee-1);
  int r = t >> 7;            // b*P + p
  int b = r / Pp;
  int node = cur[r];
  encl[(size_t)r*Ee + e] = x[((size_t)(b*NT + node))*Ee + e];
}

// q = concat(encl, load) @ Wq[129,128]
__global__ __launch_bounds__(128) void decq_k(
    const float* __restrict__ encl, const float* __restrict__ loadv,
    const float* __restrict__ Wq, float* __restrict__ q)
{
  __shared__ float row[Ee];
  int r = blockIdx.x, e = threadIdx.x;
  row[e] = encl[(size_t)r*Ee + e];
  __syncthreads();
  float acc = 0.f;
  #pragma unroll 4
  for (int k=0;k<Ee;k++) acc = fmaf(row[k], Wq[k*128 + e], acc);
  acc = fmaf(loadv[r], Wq[Ee*128 + e], acc);
  q[(size_t)r*128 + e] = acc;
}

// mh = att@W + b + encl + load*capw
__global__ __launch_bounds__(128) void dec_comb_k(
    const float* __restrict__ att, const float* __restrict__ W,
    const float* __restrict__ bias, const float* __restrict__ encl,
    const float* __restrict__ loadv, const float* __restrict__ capw,
    float* __restrict__ mh)
{
  __shared__ float row[Ee];
  int r = blockIdx.x, e = threadIdx.x;
  row[e] = att[(size_t)r*Ee + e];
  __syncthreads();
  float acc = 0.f;
  #pragma unroll 4
  for (int k=0;k<Ee;k++) acc = fmaf(row[k], W[k*Ee + e], acc);
  mh[(size_t)r*Ee + e] = acc + bias[e] + encl[(size_t)r*Ee + e] + loadv[r]*capw[e];
}

// score[b,p,n] = dot(qref[b,p], x[b,n]) / sqrt(E)
__global__ __launch_bounds__(128) void score_k(
    const float* __restrict__ qref, const float* __restrict__ x, float* __restrict__ score)
{
  __shared__ float q[Ee];
  int r = blockIdx.x;
  int b = r / Pp;
  q[threadIdx.x] = qref[(size_t)r*Ee + threadIdx.x];
  __syncthreads();
  for (int n = threadIdx.x; n < NT; n += 128){
    const float4* xr = (const float4*)(x + ((size_t)(b*NT + n))*Ee);
    float acc = 0.f;
    #pragma unroll
    for (int k=0;k<Ee/4;k++){
      float4 xv = xr[k];
      const float* qq = &q[k*4];
      acc = fmaf(qq[0],xv.x, fmaf(qq[1],xv.y, fmaf(qq[2],xv.z, fmaf(qq[3],xv.w, acc))));
    }
    score[(size_t)r*NT + n] = acc * 0.08838834764831845f;  // 1/sqrt(128)
  }
}

// ---------------------------------------------------------------- threefry noise
// jax >= 0.4.30: jax_threefry_partitionable=True.
// Element i: threefry2x32(key=(0,42), x=(0, i)), bits = out0 ^ out1.
__device__ __forceinline__ unsigned rotl32(unsigned x, int r){ return (x<<r)|(x>>(32-r)); }

__device__ float tf_normal(unsigned idx)
{
  unsigned x0 = 0u;
  unsigned x1 = idx;
  const unsigned ks[3] = {0u, 42u, 0u ^ 42u ^ 0x1BD11BDAu};
  x0 += ks[0]; x1 += ks[1];
  const int rotA[4] = {13,15,26,6};
  const int rotB[4] = {17,29,16,24};
  #pragma unroll
  for (int i=0;i<5;i++){
    #pragma unroll
    for (int q=0;q<4;q++){
      int rr = (i&1) ? rotB[q] : rotA[q];
      x0 += x1; x1 = rotl32(x1, rr); x1 ^= x0;
    }
    x0 += ks[(i+1)%3];
    x1 += ks[(i+2)%3] + (unsigned)(i+1);
  }
  unsigned bits = x0 ^ x1;
  float f = __uint_as_float((bits >> 9) | 0x3f800000u) - 1.0f;
  const float lo = -0.99999994f;
  float u = f * 2.0f + lo;
  u = fmaxf(lo, u);
  float w = -log1pf(-u*u);
  float p;
  if (w < 5.0f) {
    w -= 2.5f;
    p = 2.81022636e-08f;
    p = fmaf(p, w, 3.43273939e-07f);
    p = fmaf(p, w, -3.5233877e-06f);
    p = fmaf(p, w, -4.39150654e-06f);
    p = fmaf(p, w, 0.00021858087f);
    p = fmaf(p, w, -0.00125372503f);
    p = fmaf(p, w, -0.00417768164f);
    p = fmaf(p, w, 0.246640727f);
    p = fmaf(p, w, 1.50140941f);
  } else {
    w = sqrtf(w) - 3.0f;
    p = -0.000200214257f;
    p = fmaf(p, w, 0.000100950558f);
    p = fmaf(p, w, 0.00134934322f);
    p = fmaf(p, w, -0.00367342844f);
    p = fmaf(p, w, 0.00573950773f);
    p = fmaf(p, w, -0.0076224613f);
    p = fmaf(p, w, 0.00943887047f);
    p = fmaf(p, w, 1.00167406f);
    p = fmaf(p, w, 2.83297682f);
  }
  return 1.4142135623730951f * (p * u);
}

// ---------------------------------------------------------------- finalize (f32)
__global__ __launch_bounds__(512) void final_k(
    const float* __restrict__ score, const float* __restrict__ cur_dist,
    const float* __restrict__ ninf, float* __restrict__ out)
{
  __shared__ float red[512];
  const float NM = (float)(50.0/501.0);
  const float C1 = (float)(1.0 - 50.0/501.0);
  int r = blockIdx.x;
  int t = threadIdx.x;
  float cd = 0.f, dmn = 1e30f, dmx = -1e30f;
  if (t < NT) { cd = cur_dist[(size_t)r*NT + t]; dmn = cd; dmx = cd; }
  red[t] = dmn; __syncthreads();
  for (int s=256;s>0;s>>=1){ if (t<s) red[t]=fminf(red[t],red[t+s]); __syncthreads(); }
  float dmin = red[0]; __syncthreads();
  red[t] = dmx; __syncthreads();
  for (int s=256;s>0;s>>=1){ if (t<s) red[t]=fmaxf(red[t],red[t+s]); __syncthreads(); }
  float dmax = red[0]; __syncthreads();

  float sval = -1e30f;
  if (t < NT) {
    float nd = (cd - dmin) / (dmax - dmin + 1e-6f);
    float z  = tf_normal((unsigned)r*501u + (unsigned)t);
    float s  = score[(size_t)r*NT + t] - C1*logf(nd + 1e-6f) + (z*0.2f + 0.5f)*NM;
    sval = 10.0f*tanhf(s) + ninf[(size_t)r*NT + t];
  }
  red[t] = sval; __syncthreads();
  for (int s=256;s>0;s>>=1){ if (t<s) red[t]=fmaxf(red[t],red[t+s]); __syncthreads(); }
  float smax = red[0]; __syncthreads();
  float e = (t < NT) ? expf(sval - smax) : 0.f;
  red[t] = e; __syncthreads();
  for (int s=256;s>0;s>>=1){ if (t<s) red[t]+=red[t+s]; __syncthreads(); }
  float ssum = red[0];
  if (t < NT) out[(size_t)r*NT + t] = e / ssum;
}

// ---------------------------------------------------------------- launch
extern "C" void kernel_launch(void* const* d_in, const int* in_sizes, int n_in,
                              void* d_out, int out_size, void* d_ws, size_t ws_size,
                              hipStream_t stream)
{
  (void)in_sizes; (void)n_in; (void)out_size; (void)ws_size;
  const float* depot_xy    = (const float*)d_in[0];
  const float* node_xy     = (const float*)d_in[1];
  const float* node_demand = (const float*)d_in[2];
  const float* loadv       = (const float*)d_in[3];
  const float* cur_dist    = (const float*)d_in[4];
  const float* ninf        = (const float*)d_in[5];
  const int*   cur_node    = (const int*)d_in[6];
  const float* emb_depot_w = (const float*)d_in[7];
  const float* emb_depot_b = (const float*)d_in[8];
  const float* emb_node_w  = (const float*)d_in[9];
  const float* emb_node_b  = (const float*)d_in[10];
  const float* enc_wq      = (const float*)d_in[11];
  const float* enc_wk      = (const float*)d_in[12];
  const float* enc_wv      = (const float*)d_in[13];
  const float* enc_comb_w  = (const float*)d_in[14];
  const float* enc_comb_b  = (const float*)d_in[15];
  const float* enc_ff1_w   = (const float*)d_in[16];
  const float* enc_ff1_b   = (const float*)d_in[17];
  const float* enc_ff2_w   = (const float*)d_in[18];
  const float* enc_ff2_b   = (const float*)d_in[19];
  const float* dec_wq_last = (const float*)d_in[20];
  const float* dec_wk      = (const float*)d_in[21];
  const float* dec_wv      = (const float*)d_in[22];
  const float* dec_comb_w  = (const float*)d_in[23];
  const float* dec_comb_b  = (const float*)d_in[24];
  const float* dec_cap_w   = (const float*)d_in[25];
  const float* dec_ff1_w   = (const float*)d_in[26];
  const float* dec_ff1_b   = (const float*)d_in[27];
  const float* dec_ff2_w   = (const float*)d_in[28];
  const float* dec_ff2_b   = (const float*)d_in[29];

  float* ws = (float*)d_ws;
  const size_t SZ = (size_t)Mtok*Ee;   // 1,026,048
  float* xb    = ws + 0*SZ;
  float* qkvb  = ws + 1*SZ;            // encoder: [Mtok][384]; decoder: KV [Mtok][256]
  float* atb   = ws + 4*SZ;
  float* o1b   = ws + 5*SZ;
  float* ffb   = ws + 6*SZ;            // Mtok*Ff floats (4*SZ)
  float* encPk = ws + 10*SZ;           // 6*128*384
  float* decPk = encPk + ENCP;         // 128*256
  // decoder small buffers live in qkvb's third SZ (beyond the [Mtok][256] KV)
  float* encl  = qkvb + 2*SZ;
  float* qdec  = encl + 204800;
  float* attd  = qdec + 204800;
  float* mhb   = attd + 204800;
  float* qrefb = atb;
  float* ffh2  = ffb;
  float* scoreb= o1b;

  pack_k<<<(ENCP + DECP + 255)/256, 256, 0, stream>>>(
      enc_wq, enc_wk, enc_wv, dec_wk, dec_wv, encPk, decPk);

  embed_k<<<(Mtok*Ee + 255)/256, 256, 0, stream>>>(
      depot_xy, node_xy, node_demand, emb_depot_w, emb_depot_b,
      emb_node_w, emb_node_b, xb);

  dim3 gqkv((Mtok + 63)/64, 384/64);   // 126 x 6
  dim3 g128((Mtok + 63)/64, Ee/64);    // 126 x 2
  dim3 gff ((Mtok + 63)/64, Ff/64);    // 126 x 8
  for (int l = 0; l < Ll; ++l) {
    gemm_k<<<gqkv, 256, 0, stream>>>(xb, encPk + (size_t)l*128*384, nullptr, nullptr, qkvb, Mtok, 384, Ee, 0);
    attn_enc_k<<<Bb*Hh*2, 256, 0, stream>>>(qkvb, atb);
    gemm_k<<<g128, 256, 0, stream>>>(atb, enc_comb_w + (size_t)l*Ee*Ee, enc_comb_b + l*Ee, xb, o1b, Mtok, Ee, Ee, 0);
    gemm_k<<<gff, 256, 0, stream>>>(o1b, enc_ff1_w + (size_t)l*Ee*Ff, enc_ff1_b + l*Ff, nullptr, ffb, Mtok, Ff, Ee, 1);
    gemm_k<<<g128, 256, 0, stream>>>(ffb, enc_ff2_w + (size_t)l*Ff*Ee, enc_ff2_b + l*Ee, o1b, xb, Mtok, Ee, Ff, 0);
  }

  // decoder
  dim3 gkv((Mtok + 63)/64, 256/64);    // 126 x 4
  gemm_k<<<gkv, 256, 0, stream>>>(xb, decPk, nullptr, nullptr, qkvb, Mtok, 256, Ee, 0);
  gather_k<<<(PR*Ee + 255)/256, 256, 0, stream>>>(xb, cur_node, encl);
  decq_k<<<PR, 128, 0, stream>>>(encl, loadv, dec_wq_last, qdec);
  attn_dec_k<<<PR, 128, 0, stream>>>(qdec, qkvb, ninf, attd);
  dec_comb_k<<<PR, 128, 0, stream>>>(attd, dec_comb_w, dec_comb_b, encl, loadv, dec_cap_w, mhb);
  dim3 gd1((PR + 63)/64, Ff/64);
  gemm_k<<<gd1, 256, 0, stream>>>(mhb, dec_ff1_w, dec_ff1_b, nullptr, ffh2, PR, Ff, Ee, 1);
  dim3 gd2((PR + 63)/64, Ee/64);
  gemm_k<<<gd2, 256, 0, stream>>>(ffh2, dec_ff2_w, dec_ff2_b, mhb, qrefb, PR, Ee, Ff, 0);
  score_k<<<PR, 128, 0, stream>>>(qrefb, xb, scoreb);
  final_k<<<PR, 512, 0, stream>>>(scoreb, cur_dist, ninf, (float*)d_out);
}

// Round 7
// 1145.689 us; speedup vs baseline: 1.2134x; 1.2134x over previous
//
#include <hip/hip_runtime.h>
#include <math.h>

#define Bb 16
#define Nn 500
#define NT 501
#define Pp 100
#define Ee 128
#define Hh 8
#define Dd 16
#define Ff 512
#define Ll 6
#define Mtok (Bb*NT)   // 8016
#define PR (Bb*Pp)     // 1600
#define TJ 32          // attn_enc KV tile rows
#define SPLIT 3        // KV-split factor (501 = 3*167)
#define KSEG 167
#define ENCP (6*128*384)
#define DECP (128*256)

// ---------------------------------------------------------------- weight packing
__global__ __launch_bounds__(256) void pack_k(
    const float* __restrict__ ewq, const float* __restrict__ ewk, const float* __restrict__ ewv,
    const float* __restrict__ dwk, const float* __restrict__ dwv,
    float* __restrict__ encP, float* __restrict__ decP)
{
  int i = blockIdx.x*256 + threadIdx.x;
  if (i < ENCP) {
    int l = i / (128*384); int rem = i - l*128*384; int k = rem / 384; int n = rem - k*384;
    float v;
    if (n < 128)      v = ewq[((size_t)l*128 + k)*128 + n];
    else if (n < 256) v = ewk[((size_t)l*128 + k)*128 + (n-128)];
    else              v = ewv[((size_t)l*128 + k)*128 + (n-256)];
    encP[i] = v;
  } else {
    int j = i - ENCP;
    if (j < DECP) {
      int k = j >> 8; int n = j & 255;
      decP[j] = (n < 128) ? dwk[k*128 + n] : dwv[k*128 + (n-128)];
    }
  }
}

// ---------------------------------------------------------------- embed
__global__ __launch_bounds__(256) void embed_k(
    const float* __restrict__ depot_xy, const float* __restrict__ node_xy,
    const float* __restrict__ node_demand,
    const float* __restrict__ wD, const float* __restrict__ bD,
    const float* __restrict__ wN, const float* __restrict__ bN,
    float* __restrict__ x)
{
  int t = blockIdx.x*256 + threadIdx.x;
  if (t >= Mtok*Ee) return;
  int e   = t & (Ee-1);
  int tok = t >> 7;
  int b   = tok / NT;
  int n   = tok - b*NT;
  float v;
  if (n == 0) {
    v = depot_xy[b*2+0]*wD[0*Ee+e] + depot_xy[b*2+1]*wD[1*Ee+e] + bD[e];
  } else {
    int nn = n - 1;
    float c0 = node_xy[(b*Nn + nn)*2 + 0];
    float c1 = node_xy[(b*Nn + nn)*2 + 1];
    float c2 = node_demand[b*Nn + nn];
    v = c0*wN[0*Ee+e] + c1*wN[1*Ee+e] + c2*wN[2*Ee+e] + bN[e];
  }
  x[(size_t)tok*Ee + e] = v;
}

// ---------------------------------------------------------------- GEMM
__global__ __launch_bounds__(256) void gemm_k(
    const float* __restrict__ A, const float* __restrict__ W,
    const float* __restrict__ bias, const float* __restrict__ res,
    float* __restrict__ C, int M, int N, int K, int relu)
{
  __shared__ __align__(16) float As[16][64];
  __shared__ __align__(16) float Bs[16][64];
  int tid = threadIdx.x;
  int tx = tid & 15, ty = tid >> 4;
  int m0 = blockIdx.x * 64, n0 = blockIdx.y * 64;
  float acc[4][4];
  #pragma unroll
  for (int i=0;i<4;i++)
    #pragma unroll
    for (int j=0;j<4;j++) acc[i][j] = 0.f;

  int ar = tid >> 2;
  int ak = (tid & 3) << 2;
  int br = tid >> 4;
  int bc = (tid & 15) << 2;

  const float* Ap = A + (size_t)(m0 + ar)*K + ak;
  const float* Wp = W + (size_t)br*N + n0 + bc;
  bool aok = (m0 + ar) < M;

  float4 av = aok ? *(const float4*)(Ap) : make_float4(0.f,0.f,0.f,0.f);
  float4 wv = *(const float4*)(Wp);

  for (int k0 = 0; k0 < K; k0 += 16) {
    As[ak+0][ar] = av.x; As[ak+1][ar] = av.y; As[ak+2][ar] = av.z; As[ak+3][ar] = av.w;
    *(float4*)(&Bs[br][bc]) = wv;
    __syncthreads();
    if (k0 + 16 < K) {
      av = aok ? *(const float4*)(Ap + k0 + 16) : make_float4(0.f,0.f,0.f,0.f);
      wv = *(const float4*)(Wp + (size_t)(k0 + 16)*N);
    }
    #pragma unroll
    for (int k=0;k<16;k++){
      float4 a4 = *(const float4*)(&As[k][ty*4]);
      float4 b4 = *(const float4*)(&Bs[k][tx*4]);
      float avv[4] = {a4.x,a4.y,a4.z,a4.w};
      float bvv[4] = {b4.x,b4.y,b4.z,b4.w};
      #pragma unroll
      for (int i=0;i<4;i++)
        #pragma unroll
        for (int j=0;j<4;j++)
          acc[i][j] = fmaf(avv[i], bvv[j], acc[i][j]);
    }
    __syncthreads();
  }

  float4 bv = make_float4(0.f,0.f,0.f,0.f);
  if (bias) bv = *(const float4*)(bias + n0 + tx*4);
  #pragma unroll
  for (int i=0;i<4;i++){
    int row = m0 + ty*4 + i;
    if (row >= M) continue;
    float4 o;
    o.x = acc[i][0] + bv.x; o.y = acc[i][1] + bv.y;
    o.z = acc[i][2] + bv.z; o.w = acc[i][3] + bv.w;
    if (relu){ o.x=fmaxf(o.x,0.f); o.y=fmaxf(o.y,0.f); o.z=fmaxf(o.z,0.f); o.w=fmaxf(o.w,0.f); }
    if (res){
      float4 rv = *(const float4*)(res + (size_t)row*N + n0 + tx*4);
      o.x += rv.x; o.y += rv.y; o.z += rv.z; o.w += rv.w;
    }
    *(float4*)(C + (size_t)row*N + n0 + tx*4) = o;
  }
}

// ---------------------------------------------------------------- attention
__device__ __forceinline__ float dot4(float4 a, float4 b){
  return fmaf(a.x,b.x, fmaf(a.y,b.y, fmaf(a.z,b.z, a.w*b.w)));
}

// encoder self-attention, KV-split flash style.
// block = ((bh*2 + c)*SPLIT + s): queries c*256..(+255), keys [s*167,(s+1)*167).
// Writes UNNORMALIZED partial o[16] + (m,l) per (s,bh,query).
__global__ __launch_bounds__(256) void attn_enc_k(
    const float* __restrict__ QKV, float* __restrict__ part_o,
    float* __restrict__ part_ml)
{
  int blk = blockIdx.x;
  int s  = blk % SPLIT;
  int cc = blk / SPLIT;
  int c  = cc & 1;
  int bh = cc >> 1;
  int h  = bh & (Hh-1);
  int b  = bh >> 3;
  int p  = c*256 + (int)threadIdx.x;
  const int klo = s*KSEG;

  __shared__ __align__(16) float4 Ks[2][TJ][4];
  __shared__ __align__(16) float4 Vs[2][TJ][4];

  int tid = threadIdx.x;
  int row = (tid >> 2) & 31;        // 0..31
  int lc  = tid & 3;
  bool isV = tid >= 128;
  const int kvoff = isV ? 256 : 128;

  float4 q0,q1,q2,q3;
  if (p < NT) {
    const float4* qp = (const float4*)(QKV + ((size_t)(b*NT + p))*384 + h*Dd);
    q0=qp[0]; q1=qp[1]; q2=qp[2]; q3=qp[3];
  } else {
    q0=q1=q2=q3=make_float4(0,0,0,0);
  }

  // load tile 0
  if (row < KSEG) {
    float4 v = *((const float4*)(QKV + ((size_t)(b*NT + klo + row))*384 + kvoff + h*Dd) + lc);
    if (isV) Vs[0][row][lc] = v; else Ks[0][row][lc] = v;
  }
  __syncthreads();

  float m = -1e30f, l = 0.f;
  float4 o0=make_float4(0,0,0,0), o1=o0, o2=o0, o3=o0;
  const int ntiles = (KSEG + TJ - 1)/TJ;   // 6 (5 full + 7)
  int buf = 0;

  for (int t = 0; t < ntiles; ++t) {
    int j0 = t*TJ;
    if (t+1 < ntiles) {
      int jj = j0 + TJ + row;
      if (jj < KSEG) {
        float4 v = *((const float4*)(QKV + ((size_t)(b*NT + klo + jj))*384 + kvoff + h*Dd) + lc);
        if (isV) Vs[buf^1][row][lc] = v; else Ks[buf^1][row][lc] = v;
      }
    }
    int jend = KSEG - j0; if (jend > TJ) jend = TJ;

    if (p < NT) {
      #pragma unroll 4
      for (int jj=0;jj<jend;jj++){
        const float4* kr = &Ks[buf][jj][0];
        float s0 = (dot4(q0,kr[0])+dot4(q1,kr[1])) + (dot4(q2,kr[2])+dot4(q3,kr[3]));
        s0 *= 0.25f;
        float mn = fmaxf(m, s0);
        float cf = __expf(m - mn);
        float w  = __expf(s0 - mn);
        l = l*cf + w;
        const float4* vr = &Vs[buf][jj][0];
        float4 v0=vr[0],v1=vr[1],v2=vr[2],v3=vr[3];
        o0.x=fmaf(w,v0.x,o0.x*cf); o0.y=fmaf(w,v0.y,o0.y*cf); o0.z=fmaf(w,v0.z,o0.z*cf); o0.w=fmaf(w,v0.w,o0.w*cf);
        o1.x=fmaf(w,v1.x,o1.x*cf); o1.y=fmaf(w,v1.y,o1.y*cf); o1.z=fmaf(w,v1.z,o1.z*cf); o1.w=fmaf(w,v1.w,o1.w*cf);
        o2.x=fmaf(w,v2.x,o2.x*cf); o2.y=fmaf(w,v2.y,o2.y*cf); o2.z=fmaf(w,v2.z,o2.z*cf); o2.w=fmaf(w,v2.w,o2.w*cf);
        o3.x=fmaf(w,v3.x,o3.x*cf); o3.y=fmaf(w,v3.y,o3.y*cf); o3.z=fmaf(w,v3.z,o3.z*cf); o3.w=fmaf(w,v3.w,o3.w*cf);
        m = mn;
      }
    }
    __syncthreads();
    buf ^= 1;
  }

  if (p < NT) {
    size_t rbase = ((size_t)s*128 + bh)*NT + p;
    float4* po = (float4*)(part_o + rbase*16);
    po[0]=o0; po[1]=o1; po[2]=o2; po[3]=o3;
    part_ml[rbase*2+0] = m;
    part_ml[rbase*2+1] = l;
  }
}

// combine SPLIT partials -> O[b,q,h,d]
__global__ __launch_bounds__(256) void attn_comb_k(
    const float* __restrict__ part_o, const float* __restrict__ part_ml,
    float* __restrict__ O)
{
  int t = blockIdx.x*256 + threadIdx.x;     // ((bh*NT + q)*16 + d)
  if (t >= 128*NT*16) return;
  int d  = t & 15;
  int rq = t >> 4;          // bh*NT + q
  int q  = rq % NT;
  int bh = rq / NT;
  int h = bh & 7, b = bh >> 3;
  const size_t R = (size_t)128*NT;
  float m0 = part_ml[(0*R + rq)*2+0], l0 = part_ml[(0*R + rq)*2+1];
  float m1 = part_ml[(1*R + rq)*2+0], l1 = part_ml[(1*R + rq)*2+1];
  float m2 = part_ml[(2*R + rq)*2+0], l2 = part_ml[(2*R + rq)*2+1];
  float M = fmaxf(m0, fmaxf(m1, m2));
  float c0 = __expf(m0 - M), c1 = __expf(m1 - M), c2 = __expf(m2 - M);
  float L = l0*c0 + l1*c1 + l2*c2;
  float o = part_o[(0*R + rq)*16 + d]*c0
          + part_o[(1*R + rq)*16 + d]*c1
          + part_o[(2*R + rq)*16 + d]*c2;
  O[((size_t)(b*NT + q))*Ee + h*Dd + d] = o / L;
}

// decoder cross-attention over fused KV buffer [Mtok][256] (K|V).
__global__ __launch_bounds__(128) void attn_dec_k(
    const float* __restrict__ Q, const float* __restrict__ KV,
    const float* __restrict__ mask, float* __restrict__ O)
{
  int r = blockIdx.x;              // b*Pp + p
  int b = r / Pp;
  int t = threadIdx.x;
  int h = t >> 4;
  int ln = t & 15;
  const float4* qp = (const float4*)(Q + (size_t)r*Ee + h*Dd);
  float4 qa=qp[0], qb=qp[1], qc=qp[2], qd=qp[3];
  const float* kvb = KV + ((size_t)(b*NT))*256;
  const float* mrow = mask + (size_t)r*NT;

  float m = -1e30f, l = 0.f;
  float o[16];
  #pragma unroll
  for (int d=0; d<16; ++d) o[d] = 0.f;

  for (int j = ln; j < NT; j += 16) {
    const float4* kr = (const float4*)(kvb + (size_t)j*256 + h*Dd);
    float4 k0=kr[0],k1=kr[1],k2=kr[2],k3=kr[3];
    float s = (dot4(qa,k0)+dot4(qb,k1)) + (dot4(qc,k2)+dot4(qd,k3));
    s = s*0.25f + mrow[j];
    const float4* vr = (const float4*)(kvb + (size_t)j*256 + 128 + h*Dd);
    float4 v0=vr[0],v1=vr[1],v2=vr[2],v3=vr[3];
    float vv[16] = {v0.x,v0.y,v0.z,v0.w, v1.x,v1.y,v1.z,v1.w,
                    v2.x,v2.y,v2.z,v2.w, v3.x,v3.y,v3.z,v3.w};
    if (__any(s > m + 8.0f)) {
      float mn = fmaxf(m, s);
      float cf = __expf(m - mn);
      float w  = __expf(s - mn);
      l = l*cf + w;
      #pragma unroll
      for (int d=0; d<16; ++d) o[d] = fmaf(w, vv[d], o[d]*cf);
      m = mn;
    } else {
      float w = __expf(s - m);
      l += w;
      #pragma unroll
      for (int d=0; d<16; ++d) o[d] = fmaf(w, vv[d], o[d]);
    }
  }

  #pragma unroll
  for (int off=8; off>=1; off>>=1) {
    float m2 = __shfl_xor(m, off, 16);
    float l2 = __shfl_xor(l, off, 16);
    float mn = fmaxf(m, m2);
    float c1 = __expf(m - mn);
    float c2 = __expf(m2 - mn);
    l = l*c1 + l2*c2;
    #pragma unroll
    for (int d=0; d<16; ++d) {
      float od = __shfl_xor(o[d], off, 16);
      o[d] = o[d]*c1 + od*c2;
    }
    m = mn;
  }
  float outv = 0.f;
  #pragma unroll
  for (int d=0; d<16; ++d) outv = (ln == d) ? o[d] : outv;
  O[(size_t)r*Ee + h*Dd + ln] = outv / l;
}

// ---------------------------------------------------------------- decoder small ops
__global__ __launch_bounds__(256) void gather_k(
    const float* __restrict__ x, const int* __restrict__ cur, float* __restrict__ encl)
{
  int t = blockIdx.x*256 + threadIdx.x;
  if (t >= PR*Ee) return;
  int e = t & (Ee-1);
  int r = t >> 7;
  int b = r / Pp;
  int node = cur[r];
  encl[(size_t)r*Ee + e] = x[((size_t)(b*NT + node))*Ee + e];
}

__global__ __launch_bounds__(128) void decq_k(
    const float* __restrict__ encl, const float* __restrict__ loadv,
    const float* __restrict__ Wq, float* __restrict__ q)
{
  __shared__ float row[Ee];
  int r = blockIdx.x, e = threadIdx.x;
  row[e] = encl[(size_t)r*Ee + e];
  __syncthreads();
  float acc = 0.f;
  #pragma unroll 4
  for (int k=0;k<Ee;k++) acc = fmaf(row[k], Wq[k*128 + e], acc);
  acc = fmaf(loadv[r], Wq[Ee*128 + e], acc);
  q[(size_t)r*128 + e] = acc;
}

__global__ __launch_bounds__(128) void dec_comb_k(
    const float* __restrict__ att, const float* __restrict__ W,
    const float* __restrict__ bias, const float* __restrict__ encl,
    const float* __restrict__ loadv, const float* __restrict__ capw,
    float* __restrict__ mh)
{
  __shared__ float row[Ee];
  int r = blockIdx.x, e = threadIdx.x;
  row[e] = att[(size_t)r*Ee + e];
  __syncthreads();
  float acc = 0.f;
  #pragma unroll 4
  for (int k=0;k<Ee;k++) acc = fmaf(row[k], W[k*Ee + e], acc);
  mh[(size_t)r*Ee + e] = acc + bias[e] + encl[(size_t)r*Ee + e] + loadv[r]*capw[e];
}

__global__ __launch_bounds__(128) void score_k(
    const float* __restrict__ qref, const float* __restrict__ x, float* __restrict__ score)
{
  __shared__ float q[Ee];
  int r = blockIdx.x;
  int b = r / Pp;
  q[threadIdx.x] = qref[(size_t)r*Ee + threadIdx.x];
  __syncthreads();
  for (int n = threadIdx.x; n < NT; n += 128){
    const float4* xr = (const float4*)(x + ((size_t)(b*NT + n))*Ee);
    float acc = 0.f;
    #pragma unroll
    for (int k=0;k<Ee/4;k++){
      float4 xv = xr[k];
      const float* qq = &q[k*4];
      acc = fmaf(qq[0],xv.x, fmaf(qq[1],xv.y, fmaf(qq[2],xv.z, fmaf(qq[3],xv.w, acc))));
    }
    score[(size_t)r*NT + n] = acc * 0.08838834764831845f;
  }
}

// ---------------------------------------------------------------- threefry noise
__device__ __forceinline__ unsigned rotl32(unsigned x, int r){ return (x<<r)|(x>>(32-r)); }

__device__ float tf_normal(unsigned idx)
{
  unsigned x0 = 0u;
  unsigned x1 = idx;
  const unsigned ks[3] = {0u, 42u, 0u ^ 42u ^ 0x1BD11BDAu};
  x0 += ks[0]; x1 += ks[1];
  const int rotA[4] = {13,15,26,6};
  const int rotB[4] = {17,29,16,24};
  #pragma unroll
  for (int i=0;i<5;i++){
    #pragma unroll
    for (int q=0;q<4;q++){
      int rr = (i&1) ? rotB[q] : rotA[q];
      x0 += x1; x1 = rotl32(x1, rr); x1 ^= x0;
    }
    x0 += ks[(i+1)%3];
    x1 += ks[(i+2)%3] + (unsigned)(i+1);
  }
  unsigned bits = x0 ^ x1;
  float f = __uint_as_float((bits >> 9) | 0x3f800000u) - 1.0f;
  const float lo = -0.99999994f;
  float u = f * 2.0f + lo;
  u = fmaxf(lo, u);
  float w = -log1pf(-u*u);
  float p;
  if (w < 5.0f) {
    w -= 2.5f;
    p = 2.81022636e-08f;
    p = fmaf(p, w, 3.43273939e-07f);
    p = fmaf(p, w, -3.5233877e-06f);
    p = fmaf(p, w, -4.39150654e-06f);
    p = fmaf(p, w, 0.00021858087f);
    p = fmaf(p, w, -0.00125372503f);
    p = fmaf(p, w, -0.00417768164f);
    p = fmaf(p, w, 0.246640727f);
    p = fmaf(p, w, 1.50140941f);
  } else {
    w = sqrtf(w) - 3.0f;
    p = -0.000200214257f;
    p = fmaf(p, w, 0.000100950558f);
    p = fmaf(p, w, 0.00134934322f);
    p = fmaf(p, w, -0.00367342844f);
    p = fmaf(p, w, 0.00573950773f);
    p = fmaf(p, w, -0.0076224613f);
    p = fmaf(p, w, 0.00943887047f);
    p = fmaf(p, w, 1.00167406f);
    p = fmaf(p, w, 2.83297682f);
  }
  return 1.4142135623730951f * (p * u);
}

// ---------------------------------------------------------------- finalize (f32)
__global__ __launch_bounds__(512) void final_k(
    const float* __restrict__ score, const float* __restrict__ cur_dist,
    const float* __restrict__ ninf, float* __restrict__ out)
{
  __shared__ float red[512];
  const float NM = (float)(50.0/501.0);
  const float C1 = (float)(1.0 - 50.0/501.0);
  int r = blockIdx.x;
  int t = threadIdx.x;
  float cd = 0.f, dmn = 1e30f, dmx = -1e30f;
  if (t < NT) { cd = cur_dist[(size_t)r*NT + t]; dmn = cd; dmx = cd; }
  red[t] = dmn; __syncthreads();
  for (int s=256;s>0;s>>=1){ if (t<s) red[t]=fminf(red[t],red[t+s]); __syncthreads(); }
  float dmin = red[0]; __syncthreads();
  red[t] = dmx; __syncthreads();
  for (int s=256;s>0;s>>=1){ if (t<s) red[t]=fmaxf(red[t],red[t+s]); __syncthreads(); }
  float dmax = red[0]; __syncthreads();

  float sval = -1e30f;
  if (t < NT) {
    float nd = (cd - dmin) / (dmax - dmin + 1e-6f);
    float z  = tf_normal((unsigned)r*501u + (unsigned)t);
    float s  = score[(size_t)r*NT + t] - C1*logf(nd + 1e-6f) + (z*0.2f + 0.5f)*NM;
    sval = 10.0f*tanhf(s) + ninf[(size_t)r*NT + t];
  }
  red[t] = sval; __syncthreads();
  for (int s=256;s>0;s>>=1){ if (t<s) red[t]=fmaxf(red[t],red[t+s]); __syncthreads(); }
  float smax = red[0]; __syncthreads();
  float e = (t < NT) ? expf(sval - smax) : 0.f;
  red[t] = e; __syncthreads();
  for (int s=256;s>0;s>>=1){ if (t<s) red[t]+=red[t+s]; __syncthreads(); }
  float ssum = red[0];
  if (t < NT) out[(size_t)r*NT + t] = e / ssum;
}

// ---------------------------------------------------------------- launch
extern "C" void kernel_launch(void* const* d_in, const int* in_sizes, int n_in,
                              void* d_out, int out_size, void* d_ws, size_t ws_size,
                              hipStream_t stream)
{
  (void)in_sizes; (void)n_in; (void)out_size; (void)ws_size;
  const float* depot_xy    = (const float*)d_in[0];
  const float* node_xy     = (const float*)d_in[1];
  const float* node_demand = (const float*)d_in[2];
  const float* loadv       = (const float*)d_in[3];
  const float* cur_dist    = (const float*)d_in[4];
  const float* ninf        = (const float*)d_in[5];
  const int*   cur_node    = (const int*)d_in[6];
  const float* emb_depot_w = (const float*)d_in[7];
  const float* emb_depot_b = (const float*)d_in[8];
  const float* emb_node_w  = (const float*)d_in[9];
  const float* emb_node_b  = (const float*)d_in[10];
  const float* enc_wq      = (const float*)d_in[11];
  const float* enc_wk      = (const float*)d_in[12];
  const float* enc_wv      = (const float*)d_in[13];
  const float* enc_comb_w  = (const float*)d_in[14];
  const float* enc_comb_b  = (const float*)d_in[15];
  const float* enc_ff1_w   = (const float*)d_in[16];
  const float* enc_ff1_b   = (const float*)d_in[17];
  const float* enc_ff2_w   = (const float*)d_in[18];
  const float* enc_ff2_b   = (const float*)d_in[19];
  const float* dec_wq_last = (const float*)d_in[20];
  const float* dec_wk      = (const float*)d_in[21];
  const float* dec_wv      = (const float*)d_in[22];
  const float* dec_comb_w  = (const float*)d_in[23];
  const float* dec_comb_b  = (const float*)d_in[24];
  const float* dec_cap_w   = (const float*)d_in[25];
  const float* dec_ff1_w   = (const float*)d_in[26];
  const float* dec_ff1_b   = (const float*)d_in[27];
  const float* dec_ff2_w   = (const float*)d_in[28];
  const float* dec_ff2_b   = (const float*)d_in[29];

  float* ws = (float*)d_ws;
  const size_t SZ = (size_t)Mtok*Ee;   // 1,026,048
  float* xb    = ws + 0*SZ;
  float* qkvb  = ws + 1*SZ;            // encoder QKV [Mtok][384] (3*SZ); decoder KV [Mtok][256]
  float* atb   = ws + 4*SZ;
  float* o1b   = ws + 5*SZ;
  float* ffb   = ws + 6*SZ;            // FF scratch (4*SZ); attn partials live here pre-FF
  float* encPk = ws + 10*SZ;
  float* decPk = encPk + ENCP;
  // attention partials (inside ffb region, consumed before FF1 writes ffb)
  float* part_o  = ffb;                               // SPLIT*128*NT*16 = 3,079,104
  float* part_ml = ffb + (size_t)SPLIT*128*NT*16;     // SPLIT*128*NT*2  =   384,768
  // decoder small buffers beyond decoder KV ([Mtok][256] = 2*SZ) inside qkvb
  float* encl  = qkvb + 2*SZ;
  float* qdec  = encl + 204800;
  float* attd  = qdec + 204800;
  float* mhb   = attd + 204800;
  float* qrefb = atb;
  float* ffh2  = ffb;
  float* scoreb= o1b;

  pack_k<<<(ENCP + DECP + 255)/256, 256, 0, stream>>>(
      enc_wq, enc_wk, enc_wv, dec_wk, dec_wv, encPk, decPk);

  embed_k<<<(Mtok*Ee + 255)/256, 256, 0, stream>>>(
      depot_xy, node_xy, node_demand, emb_depot_w, emb_depot_b,
      emb_node_w, emb_node_b, xb);

  dim3 gqkv((Mtok + 63)/64, 384/64);
  dim3 g128((Mtok + 63)/64, Ee/64);
  dim3 gff ((Mtok + 63)/64, Ff/64);
  const int gcomb = (128*NT*16 + 255)/256;   // 4008
  for (int l = 0; l < Ll; ++l) {
    gemm_k<<<gqkv, 256, 0, stream>>>(xb, encPk + (size_t)l*128*384, nullptr, nullptr, qkvb, Mtok, 384, Ee, 0);
    attn_enc_k<<<Bb*Hh*2*SPLIT, 256, 0, stream>>>(qkvb, part_o, part_ml);
    attn_comb_k<<<gcomb, 256, 0, stream>>>(part_o, part_ml, atb);
    gemm_k<<<g128, 256, 0, stream>>>(atb, enc_comb_w + (size_t)l*Ee*Ee, enc_comb_b + l*Ee, xb, o1b, Mtok, Ee, Ee, 0);
    gemm_k<<<gff, 256, 0, stream>>>(o1b, enc_ff1_w + (size_t)l*Ee*Ff, enc_ff1_b + l*Ff, nullptr, ffb, Mtok, Ff, Ee, 1);
    gemm_k<<<g128, 256, 0, stream>>>(ffb, enc_ff2_w + (size_t)l*Ff*Ee, enc_ff2_b + l*Ee, o1b, xb, Mtok, Ee, Ff, 0);
  }

  // decoder
  dim3 gkv((Mtok + 63)/64, 256/64);
  gemm_k<<<gkv, 256, 0, stream>>>(xb, decPk, nullptr, nullptr, qkvb, Mtok, 256, Ee, 0);
  gather_k<<<(PR*Ee + 255)/256, 256, 0, stream>>>(xb, cur_node, encl);
  decq_k<<<PR, 128, 0, stream>>>(encl, loadv, dec_wq_last, qdec);
  attn_dec_k<<<PR, 128, 0, stream>>>(qdec, qkvb, ninf, attd);
  dec_comb_k<<<PR, 128, 0, stream>>>(attd, dec_comb_w, dec_comb_b, encl, loadv, dec_cap_w, mhb);
  dim3 gd1((PR + 63)/64, Ff/64);
  gemm_k<<<gd1, 256, 0, stream>>>(mhb, dec_ff1_w, dec_ff1_b, nullptr, ffh2, PR, Ff, Ee, 1);
  dim3 gd2((PR + 63)/64, Ee/64);
  gemm_k<<<gd2, 256, 0, stream>>>(ffh2, dec_ff2_w, dec_ff2_b, mhb, qrefb, PR, Ee, Ff, 0);
  score_k<<<PR, 128, 0, stream>>>(qrefb, xb, scoreb);
  final_k<<<PR, 512, 0, stream>>>(scoreb, cur_dist, ninf, (float*)d_out);
}

// Round 8
// 1107.968 us; speedup vs baseline: 1.2548x; 1.0340x over previous
//
#include <hip/hip_runtime.h>
#include <math.h>

#define Bb 16
#define Nn 500
#define NT 501
#define Pp 100
#define Ee 128
#define Hh 8
#define Dd 16
#define Ff 512
#define Ll 6
#define Mtok (Bb*NT)   // 8016
#define PR (Bb*Pp)     // 1600
#define TJ 32          // attn_enc KV tile rows
#define SPLIT 3        // encoder KV-split (501 = 3*167)
#define KSEG 167
#define DSPLIT 4       // decoder KV-split
#define DSEG 126       // ceil(501/4); last segment = 123
#define ENCP (6*128*384)
#define DECP (128*256)

// ---------------------------------------------------------------- weight packing
__global__ __launch_bounds__(256) void pack_k(
    const float* __restrict__ ewq, const float* __restrict__ ewk, const float* __restrict__ ewv,
    const float* __restrict__ dwk, const float* __restrict__ dwv,
    float* __restrict__ encP, float* __restrict__ decP)
{
  int i = blockIdx.x*256 + threadIdx.x;
  if (i < ENCP) {
    int l = i / (128*384); int rem = i - l*128*384; int k = rem / 384; int n = rem - k*384;
    float v;
    if (n < 128)      v = ewq[((size_t)l*128 + k)*128 + n];
    else if (n < 256) v = ewk[((size_t)l*128 + k)*128 + (n-128)];
    else              v = ewv[((size_t)l*128 + k)*128 + (n-256)];
    encP[i] = v;
  } else {
    int j = i - ENCP;
    if (j < DECP) {
      int k = j >> 8; int n = j & 255;
      decP[j] = (n < 128) ? dwk[k*128 + n] : dwv[k*128 + (n-128)];
    }
  }
}

// ---------------------------------------------------------------- embed
__global__ __launch_bounds__(256) void embed_k(
    const float* __restrict__ depot_xy, const float* __restrict__ node_xy,
    const float* __restrict__ node_demand,
    const float* __restrict__ wD, const float* __restrict__ bD,
    const float* __restrict__ wN, const float* __restrict__ bN,
    float* __restrict__ x)
{
  int t = blockIdx.x*256 + threadIdx.x;
  if (t >= Mtok*Ee) return;
  int e   = t & (Ee-1);
  int tok = t >> 7;
  int b   = tok / NT;
  int n   = tok - b*NT;
  float v;
  if (n == 0) {
    v = depot_xy[b*2+0]*wD[0*Ee+e] + depot_xy[b*2+1]*wD[1*Ee+e] + bD[e];
  } else {
    int nn = n - 1;
    float c0 = node_xy[(b*Nn + nn)*2 + 0];
    float c1 = node_xy[(b*Nn + nn)*2 + 1];
    float c2 = node_demand[b*Nn + nn];
    v = c0*wN[0*Ee+e] + c1*wN[1*Ee+e] + c2*wN[2*Ee+e] + bN[e];
  }
  x[(size_t)tok*Ee + e] = v;
}

// ---------------------------------------------------------------- GEMM
// C[M,N] = A[M,K] @ W[K,N]  (+bias)(relu)(+res).  N%64==0, K%16==0.
// Double-buffered LDS, ONE barrier per K-step (store -> barrier -> compute).
__global__ __launch_bounds__(256) void gemm_k(
    const float* __restrict__ A, const float* __restrict__ W,
    const float* __restrict__ bias, const float* __restrict__ res,
    float* __restrict__ C, int M, int N, int K, int relu)
{
  __shared__ __align__(16) float As[2][16][64];
  __shared__ __align__(16) float Bs[2][16][64];
  int tid = threadIdx.x;
  int tx = tid & 15, ty = tid >> 4;
  int m0 = blockIdx.x * 64, n0 = blockIdx.y * 64;
  float acc[4][4];
  #pragma unroll
  for (int i=0;i<4;i++)
    #pragma unroll
    for (int j=0;j<4;j++) acc[i][j] = 0.f;

  int ar = tid >> 2;          // 0..63  A row in tile
  int ak = (tid & 3) << 2;    // 0,4,8,12
  int br = tid >> 4;          // 0..15  W row in tile
  int bc = (tid & 15) << 2;   // 0..60

  const float* Ap = A + (size_t)(m0 + ar)*K + ak;
  const float* Wp = W + (size_t)br*N + n0 + bc;
  bool aok = (m0 + ar) < M;

  float4 av = aok ? *(const float4*)(Ap) : make_float4(0.f,0.f,0.f,0.f);
  float4 wv = *(const float4*)(Wp);

  int nk = K >> 4;
  for (int t = 0; t < nk; ++t) {
    int cur = t & 1;
    As[cur][ak+0][ar] = av.x; As[cur][ak+1][ar] = av.y;
    As[cur][ak+2][ar] = av.z; As[cur][ak+3][ar] = av.w;
    *(float4*)(&Bs[cur][br][bc]) = wv;
    __syncthreads();
    if (t+1 < nk) {
      av = aok ? *(const float4*)(Ap + (t+1)*16) : make_float4(0.f,0.f,0.f,0.f);
      wv = *(const float4*)(Wp + (size_t)(t+1)*16*N);
    }
    #pragma unroll
    for (int k=0;k<16;k++){
      float4 a4 = *(const float4*)(&As[cur][k][ty*4]);
      float4 b4 = *(const float4*)(&Bs[cur][k][tx*4]);
      float avv[4] = {a4.x,a4.y,a4.z,a4.w};
      float bvv[4] = {b4.x,b4.y,b4.z,b4.w};
      #pragma unroll
      for (int i=0;i<4;i++)
        #pragma unroll
        for (int j=0;j<4;j++)
          acc[i][j] = fmaf(avv[i], bvv[j], acc[i][j]);
    }
    // no trailing barrier: next store targets the other buffer, and
    // barrier #t bounds any straggler still reading it (see journal).
  }

  float4 bv = make_float4(0.f,0.f,0.f,0.f);
  if (bias) bv = *(const float4*)(bias + n0 + tx*4);
  #pragma unroll
  for (int i=0;i<4;i++){
    int row = m0 + ty*4 + i;
    if (row >= M) continue;
    float4 o;
    o.x = acc[i][0] + bv.x; o.y = acc[i][1] + bv.y;
    o.z = acc[i][2] + bv.z; o.w = acc[i][3] + bv.w;
    if (relu){ o.x=fmaxf(o.x,0.f); o.y=fmaxf(o.y,0.f); o.z=fmaxf(o.z,0.f); o.w=fmaxf(o.w,0.f); }
    if (res){
      float4 rv = *(const float4*)(res + (size_t)row*N + n0 + tx*4);
      o.x += rv.x; o.y += rv.y; o.z += rv.z; o.w += rv.w;
    }
    *(float4*)(C + (size_t)row*N + n0 + tx*4) = o;
  }
}

// ---------------------------------------------------------------- attention
__device__ __forceinline__ float dot4(float4 a, float4 b){
  return fmaf(a.x,b.x, fmaf(a.y,b.y, fmaf(a.z,b.z, a.w*b.w)));
}

// encoder self-attention, KV-split flash style (unchanged from R7).
__global__ __launch_bounds__(256) void attn_enc_k(
    const float* __restrict__ QKV, float* __restrict__ part_o,
    float* __restrict__ part_ml)
{
  int blk = blockIdx.x;
  int s  = blk % SPLIT;
  int cc = blk / SPLIT;
  int c  = cc & 1;
  int bh = cc >> 1;
  int h  = bh & (Hh-1);
  int b  = bh >> 3;
  int p  = c*256 + (int)threadIdx.x;
  const int klo = s*KSEG;

  __shared__ __align__(16) float4 Ks[2][TJ][4];
  __shared__ __align__(16) float4 Vs[2][TJ][4];

  int tid = threadIdx.x;
  int row = (tid >> 2) & 31;
  int lc  = tid & 3;
  bool isV = tid >= 128;
  const int kvoff = isV ? 256 : 128;

  float4 q0,q1,q2,q3;
  if (p < NT) {
    const float4* qp = (const float4*)(QKV + ((size_t)(b*NT + p))*384 + h*Dd);
    q0=qp[0]; q1=qp[1]; q2=qp[2]; q3=qp[3];
  } else {
    q0=q1=q2=q3=make_float4(0,0,0,0);
  }

  if (row < KSEG) {
    float4 v = *((const float4*)(QKV + ((size_t)(b*NT + klo + row))*384 + kvoff + h*Dd) + lc);
    if (isV) Vs[0][row][lc] = v; else Ks[0][row][lc] = v;
  }
  __syncthreads();

  float m = -1e30f, l = 0.f;
  float4 o0=make_float4(0,0,0,0), o1=o0, o2=o0, o3=o0;
  const int ntiles = (KSEG + TJ - 1)/TJ;
  int buf = 0;

  for (int t = 0; t < ntiles; ++t) {
    int j0 = t*TJ;
    if (t+1 < ntiles) {
      int jj = j0 + TJ + row;
      if (jj < KSEG) {
        float4 v = *((const float4*)(QKV + ((size_t)(b*NT + klo + jj))*384 + kvoff + h*Dd) + lc);
        if (isV) Vs[buf^1][row][lc] = v; else Ks[buf^1][row][lc] = v;
      }
    }
    int jend = KSEG - j0; if (jend > TJ) jend = TJ;

    if (p < NT) {
      #pragma unroll 4
      for (int jj=0;jj<jend;jj++){
        const float4* kr = &Ks[buf][jj][0];
        float s0 = (dot4(q0,kr[0])+dot4(q1,kr[1])) + (dot4(q2,kr[2])+dot4(q3,kr[3]));
        s0 *= 0.25f;
        float mn = fmaxf(m, s0);
        float cf = __expf(m - mn);
        float w  = __expf(s0 - mn);
        l = l*cf + w;
        const float4* vr = &Vs[buf][jj][0];
        float4 v0=vr[0],v1=vr[1],v2=vr[2],v3=vr[3];
        o0.x=fmaf(w,v0.x,o0.x*cf); o0.y=fmaf(w,v0.y,o0.y*cf); o0.z=fmaf(w,v0.z,o0.z*cf); o0.w=fmaf(w,v0.w,o0.w*cf);
        o1.x=fmaf(w,v1.x,o1.x*cf); o1.y=fmaf(w,v1.y,o1.y*cf); o1.z=fmaf(w,v1.z,o1.z*cf); o1.w=fmaf(w,v1.w,o1.w*cf);
        o2.x=fmaf(w,v2.x,o2.x*cf); o2.y=fmaf(w,v2.y,o2.y*cf); o2.z=fmaf(w,v2.z,o2.z*cf); o2.w=fmaf(w,v2.w,o2.w*cf);
        o3.x=fmaf(w,v3.x,o3.x*cf); o3.y=fmaf(w,v3.y,o3.y*cf); o3.z=fmaf(w,v3.z,o3.z*cf); o3.w=fmaf(w,v3.w,o3.w*cf);
        m = mn;
      }
    }
    __syncthreads();
    buf ^= 1;
  }

  if (p < NT) {
    size_t rbase = ((size_t)s*128 + bh)*NT + p;
    float4* po = (float4*)(part_o + rbase*16);
    po[0]=o0; po[1]=o1; po[2]=o2; po[3]=o3;
    part_ml[rbase*2+0] = m;
    part_ml[rbase*2+1] = l;
  }
}

__global__ __launch_bounds__(256) void attn_comb_k(
    const float* __restrict__ part_o, const float* __restrict__ part_ml,
    float* __restrict__ O)
{
  int t = blockIdx.x*256 + threadIdx.x;
  if (t >= 128*NT*16) return;
  int d  = t & 15;
  int rq = t >> 4;
  int q  = rq % NT;
  int bh = rq / NT;
  int h = bh & 7, b = bh >> 3;
  const size_t R = (size_t)128*NT;
  float m0 = part_ml[(0*R + rq)*2+0], l0 = part_ml[(0*R + rq)*2+1];
  float m1 = part_ml[(1*R + rq)*2+0], l1 = part_ml[(1*R + rq)*2+1];
  float m2 = part_ml[(2*R + rq)*2+0], l2 = part_ml[(2*R + rq)*2+1];
  float M = fmaxf(m0, fmaxf(m1, m2));
  float c0 = __expf(m0 - M), c1 = __expf(m1 - M), c2 = __expf(m2 - M);
  float L = l0*c0 + l1*c1 + l2*c2;
  float o = part_o[(0*R + rq)*16 + d]*c0
          + part_o[(1*R + rq)*16 + d]*c1
          + part_o[(2*R + rq)*16 + d]*c2;
  O[((size_t)(b*NT + q))*Ee + h*Dd + d] = o / L;
}

// decoder cross-attention v3: LDS-staged broadcast + KV-split.
// block = ((b*8+h)*DSPLIT + s); stage segment K/V in LDS (coalesced bulk),
// thread = query p (0..99): broadcast LDS reads, no cross-lane ops.
// Writes unnormalized partials; attn_dcomb_k merges.
__global__ __launch_bounds__(128) void attn_dec_k(
    const float* __restrict__ Q, const float* __restrict__ KV,
    const float* __restrict__ mask,
    float* __restrict__ part_o, float* __restrict__ part_ml)
{
  int blk = blockIdx.x;
  int s  = blk & (DSPLIT-1);
  int bh = blk >> 2;
  int h  = bh & (Hh-1);
  int b  = bh >> 3;
  int klo = s*DSEG;
  int kn  = NT - klo; if (kn > DSEG) kn = DSEG;   // 126,126,126,123

  __shared__ __align__(16) float4 Ks[DSEG][4];
  __shared__ __align__(16) float4 Vs[DSEG][4];

  int tid = threadIdx.x;
  for (int i = tid; i < kn*8; i += 128) {
    int row  = i >> 3;
    int q8   = i & 7;          // 0..3 = K quads, 4..7 = V quads
    int quad = q8 & 3;
    int isv  = q8 >> 2;
    float4 v = *(const float4*)(KV + ((size_t)(b*NT + klo + row))*256 + isv*128 + h*Dd + quad*4);
    if (isv) Vs[row][quad] = v; else Ks[row][quad] = v;
  }
  __syncthreads();

  int p = tid;
  if (p >= Pp) return;
  int r = b*Pp + p;
  const float4* qp = (const float4*)(Q + (size_t)r*Ee + h*Dd);
  float4 qa=qp[0], qb=qp[1], qc=qp[2], qd=qp[3];
  const float* mrow = mask + (size_t)r*NT + klo;

  float m = -1e30f, l = 0.f;
  float4 o0=make_float4(0,0,0,0), o1=o0, o2=o0, o3=o0;
  for (int j=0;j<kn;++j){
    float sc = (dot4(qa,Ks[j][0])+dot4(qb,Ks[j][1])) + (dot4(qc,Ks[j][2])+dot4(qd,Ks[j][3]));
    sc = sc*0.25f + mrow[j];
    float mn = fmaxf(m, sc);
    float cf = __expf(m - mn);
    float w  = __expf(sc - mn);
    l = l*cf + w;
    float4 v0=Vs[j][0],v1=Vs[j][1],v2=Vs[j][2],v3=Vs[j][3];
    o0.x=fmaf(w,v0.x,o0.x*cf); o0.y=fmaf(w,v0.y,o0.y*cf); o0.z=fmaf(w,v0.z,o0.z*cf); o0.w=fmaf(w,v0.w,o0.w*cf);
    o1.x=fmaf(w,v1.x,o1.x*cf); o1.y=fmaf(w,v1.y,o1.y*cf); o1.z=fmaf(w,v1.z,o1.z*cf); o1.w=fmaf(w,v1.w,o1.w*cf);
    o2.x=fmaf(w,v2.x,o2.x*cf); o2.y=fmaf(w,v2.y,o2.y*cf); o2.z=fmaf(w,v2.z,o2.z*cf); o2.w=fmaf(w,v2.w,o2.w*cf);
    o3.x=fmaf(w,v3.x,o3.x*cf); o3.y=fmaf(w,v3.y,o3.y*cf); o3.z=fmaf(w,v3.z,o3.z*cf); o3.w=fmaf(w,v3.w,o3.w*cf);
    m = mn;
  }

  size_t rb = ((size_t)s*PR + r)*Hh + h;
  float4* po = (float4*)(part_o + rb*16);
  po[0]=o0; po[1]=o1; po[2]=o2; po[3]=o3;
  part_ml[rb*2+0] = m;
  part_ml[rb*2+1] = l;
}

// combine DSPLIT decoder partials -> attd[r][h*16+d]
__global__ __launch_bounds__(256) void attn_dcomb_k(
    const float* __restrict__ part_o, const float* __restrict__ part_ml,
    float* __restrict__ O)
{
  int t = blockIdx.x*256 + threadIdx.x;
  if (t >= PR*Ee) return;
  int d = t & 15;
  int h = (t >> 4) & 7;
  int r = t >> 7;
  const size_t S = (size_t)PR*Hh;
  size_t rb = (size_t)r*Hh + h;
  float m0 = part_ml[(0*S + rb)*2+0], l0 = part_ml[(0*S + rb)*2+1];
  float m1 = part_ml[(1*S + rb)*2+0], l1 = part_ml[(1*S + rb)*2+1];
  float m2 = part_ml[(2*S + rb)*2+0], l2 = part_ml[(2*S + rb)*2+1];
  float m3 = part_ml[(3*S + rb)*2+0], l3 = part_ml[(3*S + rb)*2+1];
  float M = fmaxf(fmaxf(m0,m1), fmaxf(m2,m3));
  float c0=__expf(m0-M), c1=__expf(m1-M), c2=__expf(m2-M), c3=__expf(m3-M);
  float L = l0*c0 + l1*c1 + l2*c2 + l3*c3;
  float o = part_o[(0*S + rb)*16 + d]*c0 + part_o[(1*S + rb)*16 + d]*c1
          + part_o[(2*S + rb)*16 + d]*c2 + part_o[(3*S + rb)*16 + d]*c3;
  O[(size_t)r*Ee + h*Dd + d] = o / L;
}

// ---------------------------------------------------------------- decoder small ops
__global__ __launch_bounds__(256) void gather_k(
    const float* __restrict__ x, const int* __restrict__ cur, float* __restrict__ encl)
{
  int t = blockIdx.x*256 + threadIdx.x;
  if (t >= PR*Ee) return;
  int e = t & (Ee-1);
  int r = t >> 7;
  int b = r / Pp;
  int node = cur[r];
  encl[(size_t)r*Ee + e] = x[((size_t)(b*NT + node))*Ee + e];
}

__global__ __launch_bounds__(128) void decq_k(
    const float* __restrict__ encl, const float* __restrict__ loadv,
    const float* __restrict__ Wq, float* __restrict__ q)
{
  __shared__ float row[Ee];
  int r = blockIdx.x, e = threadIdx.x;
  row[e] = encl[(size_t)r*Ee + e];
  __syncthreads();
  float acc = 0.f;
  #pragma unroll 4
  for (int k=0;k<Ee;k++) acc = fmaf(row[k], Wq[k*128 + e], acc);
  acc = fmaf(loadv[r], Wq[Ee*128 + e], acc);
  q[(size_t)r*128 + e] = acc;
}

__global__ __launch_bounds__(128) void dec_comb_k(
    const float* __restrict__ att, const float* __restrict__ W,
    const float* __restrict__ bias, const float* __restrict__ encl,
    const float* __restrict__ loadv, const float* __restrict__ capw,
    float* __restrict__ mh)
{
  __shared__ float row[Ee];
  int r = blockIdx.x, e = threadIdx.x;
  row[e] = att[(size_t)r*Ee + e];
  __syncthreads();
  float acc = 0.f;
  #pragma unroll 4
  for (int k=0;k<Ee;k++) acc = fmaf(row[k], W[k*Ee + e], acc);
  mh[(size_t)r*Ee + e] = acc + bias[e] + encl[(size_t)r*Ee + e] + loadv[r]*capw[e];
}

__global__ __launch_bounds__(128) void score_k(
    const float* __restrict__ qref, const float* __restrict__ x, float* __restrict__ score)
{
  __shared__ float q[Ee];
  int r = blockIdx.x;
  int b = r / Pp;
  q[threadIdx.x] = qref[(size_t)r*Ee + threadIdx.x];
  __syncthreads();
  for (int n = threadIdx.x; n < NT; n += 128){
    const float4* xr = (const float4*)(x + ((size_t)(b*NT + n))*Ee);
    float acc = 0.f;
    #pragma unroll
    for (int k=0;k<Ee/4;k++){
      float4 xv = xr[k];
      const float* qq = &q[k*4];
      acc = fmaf(qq[0],xv.x, fmaf(qq[1],xv.y, fmaf(qq[2],xv.z, fmaf(qq[3],xv.w, acc))));
    }
    score[(size_t)r*NT + n] = acc * 0.08838834764831845f;
  }
}

// ---------------------------------------------------------------- threefry noise
__device__ __forceinline__ unsigned rotl32(unsigned x, int r){ return (x<<r)|(x>>(32-r)); }

__device__ float tf_normal(unsigned idx)
{
  unsigned x0 = 0u;
  unsigned x1 = idx;
  const unsigned ks[3] = {0u, 42u, 0u ^ 42u ^ 0x1BD11BDAu};
  x0 += ks[0]; x1 += ks[1];
  const int rotA[4] = {13,15,26,6};
  const int rotB[4] = {17,29,16,24};
  #pragma unroll
  for (int i=0;i<5;i++){
    #pragma unroll
    for (int q=0;q<4;q++){
      int rr = (i&1) ? rotB[q] : rotA[q];
      x0 += x1; x1 = rotl32(x1, rr); x1 ^= x0;
    }
    x0 += ks[(i+1)%3];
    x1 += ks[(i+2)%3] + (unsigned)(i+1);
  }
  unsigned bits = x0 ^ x1;
  float f = __uint_as_float((bits >> 9) | 0x3f800000u) - 1.0f;
  const float lo = -0.99999994f;
  float u = f * 2.0f + lo;
  u = fmaxf(lo, u);
  float w = -log1pf(-u*u);
  float p;
  if (w < 5.0f) {
    w -= 2.5f;
    p = 2.81022636e-08f;
    p = fmaf(p, w, 3.43273939e-07f);
    p = fmaf(p, w, -3.5233877e-06f);
    p = fmaf(p, w, -4.39150654e-06f);
    p = fmaf(p, w, 0.00021858087f);
    p = fmaf(p, w, -0.00125372503f);
    p = fmaf(p, w, -0.00417768164f);
    p = fmaf(p, w, 0.246640727f);
    p = fmaf(p, w, 1.50140941f);
  } else {
    w = sqrtf(w) - 3.0f;
    p = -0.000200214257f;
    p = fmaf(p, w, 0.000100950558f);
    p = fmaf(p, w, 0.00134934322f);
    p = fmaf(p, w, -0.00367342844f);
    p = fmaf(p, w, 0.00573950773f);
    p = fmaf(p, w, -0.0076224613f);
    p = fmaf(p, w, 0.00943887047f);
    p = fmaf(p, w, 1.00167406f);
    p = fmaf(p, w, 2.83297682f);
  }
  return 1.4142135623730951f * (p * u);
}

// ---------------------------------------------------------------- finalize (f32)
__global__ __launch_bounds__(512) void final_k(
    const float* __restrict__ score, const float* __restrict__ cur_dist,
    const float* __restrict__ ninf, float* __restrict__ out)
{
  __shared__ float red[512];
  const float NM = (float)(50.0/501.0);
  const float C1 = (float)(1.0 - 50.0/501.0);
  int r = blockIdx.x;
  int t = threadIdx.x;
  float cd = 0.f, dmn = 1e30f, dmx = -1e30f;
  if (t < NT) { cd = cur_dist[(size_t)r*NT + t]; dmn = cd; dmx = cd; }
  red[t] = dmn; __syncthreads();
  for (int s=256;s>0;s>>=1){ if (t<s) red[t]=fminf(red[t],red[t+s]); __syncthreads(); }
  float dmin = red[0]; __syncthreads();
  red[t] = dmx; __syncthreads();
  for (int s=256;s>0;s>>=1){ if (t<s) red[t]=fmaxf(red[t],red[t+s]); __syncthreads(); }
  float dmax = red[0]; __syncthreads();

  float sval = -1e30f;
  if (t < NT) {
    float nd = (cd - dmin) / (dmax - dmin + 1e-6f);
    float z  = tf_normal((unsigned)r*501u + (unsigned)t);
    float s  = score[(size_t)r*NT + t] - C1*logf(nd + 1e-6f) + (z*0.2f + 0.5f)*NM;
    sval = 10.0f*tanhf(s) + ninf[(size_t)r*NT + t];
  }
  red[t] = sval; __syncthreads();
  for (int s=256;s>0;s>>=1){ if (t<s) red[t]=fmaxf(red[t],red[t+s]); __syncthreads(); }
  float smax = red[0]; __syncthreads();
  float e = (t < NT) ? expf(sval - smax) : 0.f;
  red[t] = e; __syncthreads();
  for (int s=256;s>0;s>>=1){ if (t<s) red[t]+=red[t+s]; __syncthreads(); }
  float ssum = red[0];
  if (t < NT) out[(size_t)r*NT + t] = e / ssum;
}

// ---------------------------------------------------------------- launch
extern "C" void kernel_launch(void* const* d_in, const int* in_sizes, int n_in,
                              void* d_out, int out_size, void* d_ws, size_t ws_size,
                              hipStream_t stream)
{
  (void)in_sizes; (void)n_in; (void)out_size; (void)ws_size;
  const float* depot_xy    = (const float*)d_in[0];
  const float* node_xy     = (const float*)d_in[1];
  const float* node_demand = (const float*)d_in[2];
  const float* loadv       = (const float*)d_in[3];
  const float* cur_dist    = (const float*)d_in[4];
  const float* ninf        = (const float*)d_in[5];
  const int*   cur_node    = (const int*)d_in[6];
  const float* emb_depot_w = (const float*)d_in[7];
  const float* emb_depot_b = (const float*)d_in[8];
  const float* emb_node_w  = (const float*)d_in[9];
  const float* emb_node_b  = (const float*)d_in[10];
  const float* enc_wq      = (const float*)d_in[11];
  const float* enc_wk      = (const float*)d_in[12];
  const float* enc_wv      = (const float*)d_in[13];
  const float* enc_comb_w  = (const float*)d_in[14];
  const float* enc_comb_b  = (const float*)d_in[15];
  const float* enc_ff1_w   = (const float*)d_in[16];
  const float* enc_ff1_b   = (const float*)d_in[17];
  const float* enc_ff2_w   = (const float*)d_in[18];
  const float* enc_ff2_b   = (const float*)d_in[19];
  const float* dec_wq_last = (const float*)d_in[20];
  const float* dec_wk      = (const float*)d_in[21];
  const float* dec_wv      = (const float*)d_in[22];
  const float* dec_comb_w  = (const float*)d_in[23];
  const float* dec_comb_b  = (const float*)d_in[24];
  const float* dec_cap_w   = (const float*)d_in[25];
  const float* dec_ff1_w   = (const float*)d_in[26];
  const float* dec_ff1_b   = (const float*)d_in[27];
  const float* dec_ff2_w   = (const float*)d_in[28];
  const float* dec_ff2_b   = (const float*)d_in[29];

  float* ws = (float*)d_ws;
  const size_t SZ = (size_t)Mtok*Ee;   // 1,026,048
  float* xb    = ws + 0*SZ;
  float* qkvb  = ws + 1*SZ;            // enc QKV [Mtok][384]; dec KV [Mtok][256]
  float* atb   = ws + 4*SZ;
  float* o1b   = ws + 5*SZ;
  float* ffb   = ws + 6*SZ;            // FF scratch; attn partials live here pre-FF
  float* encPk = ws + 10*SZ;
  float* decPk = encPk + ENCP;
  // encoder attention partials (in ffb, consumed before FF1)
  float* part_o  = ffb;                               // SPLIT*128*NT*16
  float* part_ml = ffb + (size_t)SPLIT*128*NT*16;
  // decoder attention partials (in ffb, consumed before dec FF1)
  float* dpart_o  = ffb;                              // DSPLIT*PR*8*16 = 819200
  float* dpart_ml = ffb + (size_t)DSPLIT*PR*Hh*16;    // DSPLIT*PR*8*2  = 102400
  // decoder small buffers beyond dec KV (2*SZ) inside qkvb region
  float* encl  = qkvb + 2*SZ;
  float* qdec  = encl + 204800;
  float* attd  = qdec + 204800;
  float* mhb   = attd + 204800;
  float* qrefb = atb;
  float* ffh2  = ffb;
  float* scoreb= o1b;

  pack_k<<<(ENCP + DECP + 255)/256, 256, 0, stream>>>(
      enc_wq, enc_wk, enc_wv, dec_wk, dec_wv, encPk, decPk);

  embed_k<<<(Mtok*Ee + 255)/256, 256, 0, stream>>>(
      depot_xy, node_xy, node_demand, emb_depot_w, emb_depot_b,
      emb_node_w, emb_node_b, xb);

  dim3 gqkv((Mtok + 63)/64, 384/64);
  dim3 g128((Mtok + 63)/64, Ee/64);
  dim3 gff ((Mtok + 63)/64, Ff/64);
  const int gcomb = (128*NT*16 + 255)/256;
  for (int l = 0; l < Ll; ++l) {
    gemm_k<<<gqkv, 256, 0, stream>>>(xb, encPk + (size_t)l*128*384, nullptr, nullptr, qkvb, Mtok, 384, Ee, 0);
    attn_enc_k<<<Bb*Hh*2*SPLIT, 256, 0, stream>>>(qkvb, part_o, part_ml);
    attn_comb_k<<<gcomb, 256, 0, stream>>>(part_o, part_ml, atb);
    gemm_k<<<g128, 256, 0, stream>>>(atb, enc_comb_w + (size_t)l*Ee*Ee, enc_comb_b + l*Ee, xb, o1b, Mtok, Ee, Ee, 0);
    gemm_k<<<gff, 256, 0, stream>>>(o1b, enc_ff1_w + (size_t)l*Ee*Ff, enc_ff1_b + l*Ff, nullptr, ffb, Mtok, Ff, Ee, 1);
    gemm_k<<<g128, 256, 0, stream>>>(ffb, enc_ff2_w + (size_t)l*Ff*Ee, enc_ff2_b + l*Ee, o1b, xb, Mtok, Ee, Ff, 0);
  }

  // decoder
  dim3 gkv((Mtok + 63)/64, 256/64);
  gemm_k<<<gkv, 256, 0, stream>>>(xb, decPk, nullptr, nullptr, qkvb, Mtok, 256, Ee, 0);
  gather_k<<<(PR*Ee + 255)/256, 256, 0, stream>>>(xb, cur_node, encl);
  decq_k<<<PR, 128, 0, stream>>>(encl, loadv, dec_wq_last, qdec);
  attn_dec_k<<<Bb*Hh*DSPLIT, 128, 0, stream>>>(qdec, qkvb, ninf, dpart_o, dpart_ml);
  attn_dcomb_k<<<(PR*Ee + 255)/256, 256, 0, stream>>>(dpart_o, dpart_ml, attd);
  dec_comb_k<<<PR, 128, 0, stream>>>(attd, dec_comb_w, dec_comb_b, encl, loadv, dec_cap_w, mhb);
  dim3 gd1((PR + 63)/64, Ff/64);
  gemm_k<<<gd1, 256, 0, stream>>>(mhb, dec_ff1_w, dec_ff1_b, nullptr, ffh2, PR, Ff, Ee, 1);
  dim3 gd2((PR + 63)/64, Ee/64);
  gemm_k<<<gd2, 256, 0, stream>>>(ffh2, dec_ff2_w, dec_ff2_b, mhb, qrefb, PR, Ee, Ff, 0);
  score_k<<<PR, 128, 0, stream>>>(qrefb, xb, scoreb);
  final_k<<<PR, 512, 0, stream>>>(scoreb, cur_dist, ninf, (float*)d_out);
}

// Round 9
// 968.500 us; speedup vs baseline: 1.4354x; 1.1440x over previous
//
#include <hip/hip_runtime.h>
#include <math.h>

#define Bb 16
#define Nn 500
#define NT 501
#define Pp 100
#define Ee 128
#define Hh 8
#define Dd 16
#define Ff 512
#define Ll 6
#define Mtok (Bb*NT)   // 8016
#define PR (Bb*Pp)     // 1600
#define TJ 32          // attn_enc KV tile rows
#define SPLIT 4        // encoder KV-split (126,126,126,123)
#define KSEG 126
#define DSPLIT 4       // decoder KV-split
#define DSEG 126
#define ENCP (6*128*384)
#define DECP (128*256)

// ---------------------------------------------------------------- weight packing
__global__ __launch_bounds__(256) void pack_k(
    const float* __restrict__ ewq, const float* __restrict__ ewk, const float* __restrict__ ewv,
    const float* __restrict__ dwk, const float* __restrict__ dwv,
    float* __restrict__ encP, float* __restrict__ decP)
{
  int i = blockIdx.x*256 + threadIdx.x;
  if (i < ENCP) {
    int l = i / (128*384); int rem = i - l*128*384; int k = rem / 384; int n = rem - k*384;
    float v;
    if (n < 128)      v = ewq[((size_t)l*128 + k)*128 + n];
    else if (n < 256) v = ewk[((size_t)l*128 + k)*128 + (n-128)];
    else              v = ewv[((size_t)l*128 + k)*128 + (n-256)];
    encP[i] = v;
  } else {
    int j = i - ENCP;
    if (j < DECP) {
      int k = j >> 8; int n = j & 255;
      decP[j] = (n < 128) ? dwk[k*128 + n] : dwv[k*128 + (n-128)];
    }
  }
}

// ---------------------------------------------------------------- embed
__global__ __launch_bounds__(256) void embed_k(
    const float* __restrict__ depot_xy, const float* __restrict__ node_xy,
    const float* __restrict__ node_demand,
    const float* __restrict__ wD, const float* __restrict__ bD,
    const float* __restrict__ wN, const float* __restrict__ bN,
    float* __restrict__ x)
{
  int t = blockIdx.x*256 + threadIdx.x;
  if (t >= Mtok*Ee) return;
  int e   = t & (Ee-1);
  int tok = t >> 7;
  int b   = tok / NT;
  int n   = tok - b*NT;
  float v;
  if (n == 0) {
    v = depot_xy[b*2+0]*wD[0*Ee+e] + depot_xy[b*2+1]*wD[1*Ee+e] + bD[e];
  } else {
    int nn = n - 1;
    float c0 = node_xy[(b*Nn + nn)*2 + 0];
    float c1 = node_xy[(b*Nn + nn)*2 + 1];
    float c2 = node_demand[b*Nn + nn];
    v = c0*wN[0*Ee+e] + c1*wN[1*Ee+e] + c2*wN[2*Ee+e] + bN[e];
  }
  x[(size_t)tok*Ee + e] = v;
}

// ---------------------------------------------------------------- GEMM
// C[M,N] = A[M,K] @ W[K,N]  (+bias)(relu)(+res).  N%64==0, K%16==0.
// Double-buffered LDS, ONE barrier per K-step.
__global__ __launch_bounds__(256) void gemm_k(
    const float* __restrict__ A, const float* __restrict__ W,
    const float* __restrict__ bias, const float* __restrict__ res,
    float* __restrict__ C, int M, int N, int K, int relu)
{
  __shared__ __align__(16) float As[2][16][64];
  __shared__ __align__(16) float Bs[2][16][64];
  int tid = threadIdx.x;
  int tx = tid & 15, ty = tid >> 4;
  int m0 = blockIdx.x * 64, n0 = blockIdx.y * 64;
  float acc[4][4];
  #pragma unroll
  for (int i=0;i<4;i++)
    #pragma unroll
    for (int j=0;j<4;j++) acc[i][j] = 0.f;

  int ar = tid >> 2;
  int ak = (tid & 3) << 2;
  int br = tid >> 4;
  int bc = (tid & 15) << 2;

  const float* Ap = A + (size_t)(m0 + ar)*K + ak;
  const float* Wp = W + (size_t)br*N + n0 + bc;
  bool aok = (m0 + ar) < M;

  float4 av = aok ? *(const float4*)(Ap) : make_float4(0.f,0.f,0.f,0.f);
  float4 wv = *(const float4*)(Wp);

  int nk = K >> 4;
  for (int t = 0; t < nk; ++t) {
    int cur = t & 1;
    As[cur][ak+0][ar] = av.x; As[cur][ak+1][ar] = av.y;
    As[cur][ak+2][ar] = av.z; As[cur][ak+3][ar] = av.w;
    *(float4*)(&Bs[cur][br][bc]) = wv;
    __syncthreads();
    if (t+1 < nk) {
      av = aok ? *(const float4*)(Ap + (t+1)*16) : make_float4(0.f,0.f,0.f,0.f);
      wv = *(const float4*)(Wp + (size_t)(t+1)*16*N);
    }
    #pragma unroll
    for (int k=0;k<16;k++){
      float4 a4 = *(const float4*)(&As[cur][k][ty*4]);
      float4 b4 = *(const float4*)(&Bs[cur][k][tx*4]);
      float avv[4] = {a4.x,a4.y,a4.z,a4.w};
      float bvv[4] = {b4.x,b4.y,b4.z,b4.w};
      #pragma unroll
      for (int i=0;i<4;i++)
        #pragma unroll
        for (int j=0;j<4;j++)
          acc[i][j] = fmaf(avv[i], bvv[j], acc[i][j]);
    }
  }

  float4 bv = make_float4(0.f,0.f,0.f,0.f);
  if (bias) bv = *(const float4*)(bias + n0 + tx*4);
  #pragma unroll
  for (int i=0;i<4;i++){
    int row = m0 + ty*4 + i;
    if (row >= M) continue;
    float4 o;
    o.x = acc[i][0] + bv.x; o.y = acc[i][1] + bv.y;
    o.z = acc[i][2] + bv.z; o.w = acc[i][3] + bv.w;
    if (relu){ o.x=fmaxf(o.x,0.f); o.y=fmaxf(o.y,0.f); o.z=fmaxf(o.z,0.f); o.w=fmaxf(o.w,0.f); }
    if (res){
      float4 rv = *(const float4*)(res + (size_t)row*N + n0 + tx*4);
      o.x += rv.x; o.y += rv.y; o.z += rv.z; o.w += rv.w;
    }
    *(float4*)(C + (size_t)row*N + n0 + tx*4) = o;
  }
}

// ---------------------------------------------------------------- attention
__device__ __forceinline__ float dot4(float4 a, float4 b){
  return fmaf(a.x,b.x, fmaf(a.y,b.y, fmaf(a.z,b.z, a.w*b.w)));
}

// encoder self-attention, KV-split, NO max-tracking (scores provably tiny;
// o/l invariant to max shift). Writes unnormalized o + l per (s,bh,query).
__global__ __launch_bounds__(256) void attn_enc_k(
    const float* __restrict__ QKV, float* __restrict__ part_o,
    float* __restrict__ part_l)
{
  int blk = blockIdx.x;
  int s  = blk % SPLIT;
  int cc = blk / SPLIT;
  int c  = cc & 1;
  int bh = cc >> 1;
  int h  = bh & (Hh-1);
  int b  = bh >> 3;
  int p  = c*256 + (int)threadIdx.x;
  const int klo = s*KSEG;
  int kseg = NT - klo; if (kseg > KSEG) kseg = KSEG;   // 126,126,126,123

  __shared__ __align__(16) float4 Ks[2][TJ][4];
  __shared__ __align__(16) float4 Vs[2][TJ][4];

  int tid = threadIdx.x;
  int row = (tid >> 2) & 31;
  int lc  = tid & 3;
  bool isV = tid >= 128;
  const int kvoff = isV ? 256 : 128;

  float4 q0,q1,q2,q3;
  if (p < NT) {
    const float4* qp = (const float4*)(QKV + ((size_t)(b*NT + p))*384 + h*Dd);
    q0=qp[0]; q1=qp[1]; q2=qp[2]; q3=qp[3];
  } else {
    q0=q1=q2=q3=make_float4(0,0,0,0);
  }

  if (row < kseg) {
    float4 v = *((const float4*)(QKV + ((size_t)(b*NT + klo + row))*384 + kvoff + h*Dd) + lc);
    if (isV) Vs[0][row][lc] = v; else Ks[0][row][lc] = v;
  }
  __syncthreads();

  float l = 0.f;
  float4 o0=make_float4(0,0,0,0), o1=o0, o2=o0, o3=o0;
  const int ntiles = (kseg + TJ - 1)/TJ;
  int buf = 0;

  for (int t = 0; t < ntiles; ++t) {
    int j0 = t*TJ;
    if (t+1 < ntiles) {
      int jj = j0 + TJ + row;
      if (jj < kseg) {
        float4 v = *((const float4*)(QKV + ((size_t)(b*NT + klo + jj))*384 + kvoff + h*Dd) + lc);
        if (isV) Vs[buf^1][row][lc] = v; else Ks[buf^1][row][lc] = v;
      }
    }
    int jend = kseg - j0; if (jend > TJ) jend = TJ;

    if (p < NT) {
      #pragma unroll 4
      for (int jj=0;jj<jend;jj++){
        const float4* kr = &Ks[buf][jj][0];
        float s0 = (dot4(q0,kr[0])+dot4(q1,kr[1])) + (dot4(q2,kr[2])+dot4(q3,kr[3]));
        float w = __expf(s0 * 0.25f);
        l += w;
        const float4* vr = &Vs[buf][jj][0];
        float4 v0=vr[0],v1=vr[1],v2=vr[2],v3=vr[3];
        o0.x=fmaf(w,v0.x,o0.x); o0.y=fmaf(w,v0.y,o0.y); o0.z=fmaf(w,v0.z,o0.z); o0.w=fmaf(w,v0.w,o0.w);
        o1.x=fmaf(w,v1.x,o1.x); o1.y=fmaf(w,v1.y,o1.y); o1.z=fmaf(w,v1.z,o1.z); o1.w=fmaf(w,v1.w,o1.w);
        o2.x=fmaf(w,v2.x,o2.x); o2.y=fmaf(w,v2.y,o2.y); o2.z=fmaf(w,v2.z,o2.z); o2.w=fmaf(w,v2.w,o2.w);
        o3.x=fmaf(w,v3.x,o3.x); o3.y=fmaf(w,v3.y,o3.y); o3.z=fmaf(w,v3.z,o3.z); o3.w=fmaf(w,v3.w,o3.w);
      }
    }
    __syncthreads();
    buf ^= 1;
  }

  if (p < NT) {
    size_t rbase = ((size_t)s*128 + bh)*NT + p;
    float4* po = (float4*)(part_o + rbase*16);
    po[0]=o0; po[1]=o1; po[2]=o2; po[3]=o3;
    part_l[rbase] = l;
  }
}

// combine SPLIT partials (plain sums) -> O[b,q,h,d]
__global__ __launch_bounds__(256) void attn_comb_k(
    const float* __restrict__ part_o, const float* __restrict__ part_l,
    float* __restrict__ O)
{
  int t = blockIdx.x*256 + threadIdx.x;
  if (t >= 128*NT*16) return;
  int d  = t & 15;
  int rq = t >> 4;
  int q  = rq % NT;
  int bh = rq / NT;
  int h = bh & 7, b = bh >> 3;
  const size_t R = (size_t)128*NT;
  float L = 0.f, o = 0.f;
  #pragma unroll
  for (int s=0;s<SPLIT;s++){
    L += part_l[(size_t)s*R + rq];
    o += part_o[((size_t)s*R + rq)*16 + d];
  }
  O[((size_t)(b*NT + q))*Ee + h*Dd + d] = o / L;
}

// decoder cross-attention: LDS-staged broadcast + KV-split, no max-tracking.
__global__ __launch_bounds__(128) void attn_dec_k(
    const float* __restrict__ Q, const float* __restrict__ KV,
    const float* __restrict__ mask,
    float* __restrict__ part_o, float* __restrict__ part_l)
{
  int blk = blockIdx.x;
  int s  = blk & (DSPLIT-1);
  int bh = blk >> 2;
  int h  = bh & (Hh-1);
  int b  = bh >> 3;
  int klo = s*DSEG;
  int kn  = NT - klo; if (kn > DSEG) kn = DSEG;

  __shared__ __align__(16) float4 Ks[DSEG][4];
  __shared__ __align__(16) float4 Vs[DSEG][4];

  int tid = threadIdx.x;
  for (int i = tid; i < kn*8; i += 128) {
    int row  = i >> 3;
    int q8   = i & 7;
    int quad = q8 & 3;
    int isv  = q8 >> 2;
    float4 v = *(const float4*)(KV + ((size_t)(b*NT + klo + row))*256 + isv*128 + h*Dd + quad*4);
    if (isv) Vs[row][quad] = v; else Ks[row][quad] = v;
  }
  __syncthreads();

  int p = tid;
  if (p >= Pp) return;
  int r = b*Pp + p;
  const float4* qp = (const float4*)(Q + (size_t)r*Ee + h*Dd);
  float4 qa=qp[0], qb=qp[1], qc=qp[2], qd=qp[3];
  const float* mrow = mask + (size_t)r*NT + klo;

  float l = 0.f;
  float4 o0=make_float4(0,0,0,0), o1=o0, o2=o0, o3=o0;
  for (int j=0;j<kn;++j){
    float sc = (dot4(qa,Ks[j][0])+dot4(qb,Ks[j][1])) + (dot4(qc,Ks[j][2])+dot4(qd,Ks[j][3]));
    float w = __expf(sc*0.25f + mrow[j]);
    l += w;
    float4 v0=Vs[j][0],v1=Vs[j][1],v2=Vs[j][2],v3=Vs[j][3];
    o0.x=fmaf(w,v0.x,o0.x); o0.y=fmaf(w,v0.y,o0.y); o0.z=fmaf(w,v0.z,o0.z); o0.w=fmaf(w,v0.w,o0.w);
    o1.x=fmaf(w,v1.x,o1.x); o1.y=fmaf(w,v1.y,o1.y); o1.z=fmaf(w,v1.z,o1.z); o1.w=fmaf(w,v1.w,o1.w);
    o2.x=fmaf(w,v2.x,o2.x); o2.y=fmaf(w,v2.y,o2.y); o2.z=fmaf(w,v2.z,o2.z); o2.w=fmaf(w,v2.w,o2.w);
    o3.x=fmaf(w,v3.x,o3.x); o3.y=fmaf(w,v3.y,o3.y); o3.z=fmaf(w,v3.z,o3.z); o3.w=fmaf(w,v3.w,o3.w);
  }

  size_t rb = ((size_t)s*PR + r)*Hh + h;
  float4* po = (float4*)(part_o + rb*16);
  po[0]=o0; po[1]=o1; po[2]=o2; po[3]=o3;
  part_l[rb] = l;
}

// combine DSPLIT decoder partials (plain sums)
__global__ __launch_bounds__(256) void attn_dcomb_k(
    const float* __restrict__ part_o, const float* __restrict__ part_l,
    float* __restrict__ O)
{
  int t = blockIdx.x*256 + threadIdx.x;
  if (t >= PR*Ee) return;
  int d = t & 15;
  int h = (t >> 4) & 7;
  int r = t >> 7;
  const size_t S = (size_t)PR*Hh;
  size_t rb = (size_t)r*Hh + h;
  float L = 0.f, o = 0.f;
  #pragma unroll
  for (int s=0;s<DSPLIT;s++){
    L += part_l[(size_t)s*S + rb];
    o += part_o[((size_t)s*S + rb)*16 + d];
  }
  O[(size_t)r*Ee + h*Dd + d] = o / L;
}

// ---------------------------------------------------------------- decoder small ops
__global__ __launch_bounds__(256) void gather_k(
    const float* __restrict__ x, const int* __restrict__ cur, float* __restrict__ encl)
{
  int t = blockIdx.x*256 + threadIdx.x;
  if (t >= PR*Ee) return;
  int e = t & (Ee-1);
  int r = t >> 7;
  int b = r / Pp;
  int node = cur[r];
  encl[(size_t)r*Ee + e] = x[((size_t)(b*NT + node))*Ee + e];
}

__global__ __launch_bounds__(128) void decq_k(
    const float* __restrict__ encl, const float* __restrict__ loadv,
    const float* __restrict__ Wq, float* __restrict__ q)
{
  __shared__ float row[Ee];
  int r = blockIdx.x, e = threadIdx.x;
  row[e] = encl[(size_t)r*Ee + e];
  __syncthreads();
  float acc = 0.f;
  #pragma unroll 4
  for (int k=0;k<Ee;k++) acc = fmaf(row[k], Wq[k*128 + e], acc);
  acc = fmaf(loadv[r], Wq[Ee*128 + e], acc);
  q[(size_t)r*128 + e] = acc;
}

__global__ __launch_bounds__(128) void dec_comb_k(
    const float* __restrict__ att, const float* __restrict__ W,
    const float* __restrict__ bias, const float* __restrict__ encl,
    const float* __restrict__ loadv, const float* __restrict__ capw,
    float* __restrict__ mh)
{
  __shared__ float row[Ee];
  int r = blockIdx.x, e = threadIdx.x;
  row[e] = att[(size_t)r*Ee + e];
  __syncthreads();
  float acc = 0.f;
  #pragma unroll 4
  for (int k=0;k<Ee;k++) acc = fmaf(row[k], W[k*Ee + e], acc);
  mh[(size_t)r*Ee + e] = acc + bias[e] + encl[(size_t)r*Ee + e] + loadv[r]*capw[e];
}

__global__ __launch_bounds__(128) void score_k(
    const float* __restrict__ qref, const float* __restrict__ x, float* __restrict__ score)
{
  __shared__ float q[Ee];
  int r = blockIdx.x;
  int b = r / Pp;
  q[threadIdx.x] = qref[(size_t)r*Ee + threadIdx.x];
  __syncthreads();
  for (int n = threadIdx.x; n < NT; n += 128){
    const float4* xr = (const float4*)(x + ((size_t)(b*NT + n))*Ee);
    float acc = 0.f;
    #pragma unroll
    for (int k=0;k<Ee/4;k++){
      float4 xv = xr[k];
      const float* qq = &q[k*4];
      acc = fmaf(qq[0],xv.x, fmaf(qq[1],xv.y, fmaf(qq[2],xv.z, fmaf(qq[3],xv.w, acc))));
    }
    score[(size_t)r*NT + n] = acc * 0.08838834764831845f;
  }
}

// ---------------------------------------------------------------- threefry noise
__device__ __forceinline__ unsigned rotl32(unsigned x, int r){ return (x<<r)|(x>>(32-r)); }

__device__ float tf_normal(unsigned idx)
{
  unsigned x0 = 0u;
  unsigned x1 = idx;
  const unsigned ks[3] = {0u, 42u, 0u ^ 42u ^ 0x1BD11BDAu};
  x0 += ks[0]; x1 += ks[1];
  const int rotA[4] = {13,15,26,6};
  const int rotB[4] = {17,29,16,24};
  #pragma unroll
  for (int i=0;i<5;i++){
    #pragma unroll
    for (int q=0;q<4;q++){
      int rr = (i&1) ? rotB[q] : rotA[q];
      x0 += x1; x1 = rotl32(x1, rr); x1 ^= x0;
    }
    x0 += ks[(i+1)%3];
    x1 += ks[(i+2)%3] + (unsigned)(i+1);
  }
  unsigned bits = x0 ^ x1;
  float f = __uint_as_float((bits >> 9) | 0x3f800000u) - 1.0f;
  const float lo = -0.99999994f;
  float u = f * 2.0f + lo;
  u = fmaxf(lo, u);
  float w = -log1pf(-u*u);
  float p;
  if (w < 5.0f) {
    w -= 2.5f;
    p = 2.81022636e-08f;
    p = fmaf(p, w, 3.43273939e-07f);
    p = fmaf(p, w, -3.5233877e-06f);
    p = fmaf(p, w, -4.39150654e-06f);
    p = fmaf(p, w, 0.00021858087f);
    p = fmaf(p, w, -0.00125372503f);
    p = fmaf(p, w, -0.00417768164f);
    p = fmaf(p, w, 0.246640727f);
    p = fmaf(p, w, 1.50140941f);
  } else {
    w = sqrtf(w) - 3.0f;
    p = -0.000200214257f;
    p = fmaf(p, w, 0.000100950558f);
    p = fmaf(p, w, 0.00134934322f);
    p = fmaf(p, w, -0.00367342844f);
    p = fmaf(p, w, 0.00573950773f);
    p = fmaf(p, w, -0.0076224613f);
    p = fmaf(p, w, 0.00943887047f);
    p = fmaf(p, w, 1.00167406f);
    p = fmaf(p, w, 2.83297682f);
  }
  return 1.4142135623730951f * (p * u);
}

// ---------------------------------------------------------------- finalize (f32)
__global__ __launch_bounds__(512) void final_k(
    const float* __restrict__ score, const float* __restrict__ cur_dist,
    const float* __restrict__ ninf, float* __restrict__ out)
{
  __shared__ float red[512];
  const float NM = (float)(50.0/501.0);
  const float C1 = (float)(1.0 - 50.0/501.0);
  int r = blockIdx.x;
  int t = threadIdx.x;
  float cd = 0.f, dmn = 1e30f, dmx = -1e30f;
  if (t < NT) { cd = cur_dist[(size_t)r*NT + t]; dmn = cd; dmx = cd; }
  red[t] = dmn; __syncthreads();
  for (int s=256;s>0;s>>=1){ if (t<s) red[t]=fminf(red[t],red[t+s]); __syncthreads(); }
  float dmin = red[0]; __syncthreads();
  red[t] = dmx; __syncthreads();
  for (int s=256;s>0;s>>=1){ if (t<s) red[t]=fmaxf(red[t],red[t+s]); __syncthreads(); }
  float dmax = red[0]; __syncthreads();

  float sval = -1e30f;
  if (t < NT) {
    float nd = (cd - dmin) / (dmax - dmin + 1e-6f);
    float z  = tf_normal((unsigned)r*501u + (unsigned)t);
    float s  = score[(size_t)r*NT + t] - C1*logf(nd + 1e-6f) + (z*0.2f + 0.5f)*NM;
    sval = 10.0f*tanhf(s) + ninf[(size_t)r*NT + t];
  }
  red[t] = sval; __syncthreads();
  for (int s=256;s>0;s>>=1){ if (t<s) red[t]=fmaxf(red[t],red[t+s]); __syncthreads(); }
  float smax = red[0]; __syncthreads();
  float e = (t < NT) ? expf(sval - smax) : 0.f;
  red[t] = e; __syncthreads();
  for (int s=256;s>0;s>>=1){ if (t<s) red[t]+=red[t+s]; __syncthreads(); }
  float ssum = red[0];
  if (t < NT) out[(size_t)r*NT + t] = e / ssum;
}

// ---------------------------------------------------------------- launch
extern "C" void kernel_launch(void* const* d_in, const int* in_sizes, int n_in,
                              void* d_out, int out_size, void* d_ws, size_t ws_size,
                              hipStream_t stream)
{
  (void)in_sizes; (void)n_in; (void)out_size; (void)ws_size;
  const float* depot_xy    = (const float*)d_in[0];
  const float* node_xy     = (const float*)d_in[1];
  const float* node_demand = (const float*)d_in[2];
  const float* loadv       = (const float*)d_in[3];
  const float* cur_dist    = (const float*)d_in[4];
  const float* ninf        = (const float*)d_in[5];
  const int*   cur_node    = (const int*)d_in[6];
  const float* emb_depot_w = (const float*)d_in[7];
  const float* emb_depot_b = (const float*)d_in[8];
  const float* emb_node_w  = (const float*)d_in[9];
  const float* emb_node_b  = (const float*)d_in[10];
  const float* enc_wq      = (const float*)d_in[11];
  const float* enc_wk      = (const float*)d_in[12];
  const float* enc_wv      = (const float*)d_in[13];
  const float* enc_comb_w  = (const float*)d_in[14];
  const float* enc_comb_b  = (const float*)d_in[15];
  const float* enc_ff1_w   = (const float*)d_in[16];
  const float* enc_ff1_b   = (const float*)d_in[17];
  const float* enc_ff2_w   = (const float*)d_in[18];
  const float* enc_ff2_b   = (const float*)d_in[19];
  const float* dec_wq_last = (const float*)d_in[20];
  const float* dec_wk      = (const float*)d_in[21];
  const float* dec_wv      = (const float*)d_in[22];
  const float* dec_comb_w  = (const float*)d_in[23];
  const float* dec_comb_b  = (const float*)d_in[24];
  const float* dec_cap_w   = (const float*)d_in[25];
  const float* dec_ff1_w   = (const float*)d_in[26];
  const float* dec_ff1_b   = (const float*)d_in[27];
  const float* dec_ff2_w   = (const float*)d_in[28];
  const float* dec_ff2_b   = (const float*)d_in[29];

  float* ws = (float*)d_ws;
  const size_t SZ = (size_t)Mtok*Ee;   // 1,026,048
  float* xb    = ws + 0*SZ;
  float* qkvb  = ws + 1*SZ;            // enc QKV [Mtok][384]; dec KV [Mtok][256]
  float* atb   = ws + 4*SZ;
  float* o1b   = ws + 5*SZ;
  float* ffb   = ws + 6*SZ;            // FF scratch (4*SZ)
  float* encPk = ws + 10*SZ;
  float* decPk = encPk + ENCP;
  // encoder attention partials: part_o = ffb (SPLIT*128*NT*16 = 4*SZ exactly),
  // part_l -> o1b (SPLIT*128*NT = 256,512 < SZ). Both consumed before comb/ff1 write.
  float* part_o = ffb;
  float* part_l = o1b;
  // decoder attention partials (in ffb/o1b, consumed before dec FF1/score)
  float* dpart_o = ffb;                               // DSPLIT*PR*8*16 = 819,200
  float* dpart_l = o1b;                               // DSPLIT*PR*8    =  51,200
  // decoder small buffers beyond dec KV (2*SZ) inside qkvb region
  float* encl  = qkvb + 2*SZ;
  float* qdec  = encl + 204800;
  float* attd  = qdec + 204800;
  float* mhb   = attd + 204800;
  float* qrefb = atb;
  float* ffh2  = ffb;
  float* scoreb= o1b;

  pack_k<<<(ENCP + DECP + 255)/256, 256, 0, stream>>>(
      enc_wq, enc_wk, enc_wv, dec_wk, dec_wv, encPk, decPk);

  embed_k<<<(Mtok*Ee + 255)/256, 256, 0, stream>>>(
      depot_xy, node_xy, node_demand, emb_depot_w, emb_depot_b,
      emb_node_w, emb_node_b, xb);

  dim3 gqkv((Mtok + 63)/64, 384/64);
  dim3 g128((Mtok + 63)/64, Ee/64);
  dim3 gff ((Mtok + 63)/64, Ff/64);
  const int gcomb = (128*NT*16 + 255)/256;
  for (int l = 0; l < Ll; ++l) {
    gemm_k<<<gqkv, 256, 0, stream>>>(xb, encPk + (size_t)l*128*384, nullptr, nullptr, qkvb, Mtok, 384, Ee, 0);
    attn_enc_k<<<Bb*Hh*2*SPLIT, 256, 0, stream>>>(qkvb, part_o, part_l);
    attn_comb_k<<<gcomb, 256, 0, stream>>>(part_o, part_l, atb);
    gemm_k<<<g128, 256, 0, stream>>>(atb, enc_comb_w + (size_t)l*Ee*Ee, enc_comb_b + l*Ee, xb, o1b, Mtok, Ee, Ee, 0);
    gemm_k<<<gff, 256, 0, stream>>>(o1b, enc_ff1_w + (size_t)l*Ee*Ff, enc_ff1_b + l*Ff, nullptr, ffb, Mtok, Ff, Ee, 1);
    gemm_k<<<g128, 256, 0, stream>>>(ffb, enc_ff2_w + (size_t)l*Ff*Ee, enc_ff2_b + l*Ee, o1b, xb, Mtok, Ee, Ff, 0);
  }

  // decoder
  dim3 gkv((Mtok + 63)/64, 256/64);
  gemm_k<<<gkv, 256, 0, stream>>>(xb, decPk, nullptr, nullptr, qkvb, Mtok, 256, Ee, 0);
  gather_k<<<(PR*Ee + 255)/256, 256, 0, stream>>>(xb, cur_node, encl);
  decq_k<<<PR, 128, 0, stream>>>(encl, loadv, dec_wq_last, qdec);
  attn_dec_k<<<Bb*Hh*DSPLIT, 128, 0, stream>>>(qdec, qkvb, ninf, dpart_o, dpart_l);
  attn_dcomb_k<<<(PR*Ee + 255)/256, 256, 0, stream>>>(dpart_o, dpart_l, attd);
  dec_comb_k<<<PR, 128, 0, stream>>>(attd, dec_comb_w, dec_comb_b, encl, loadv, dec_cap_w, mhb);
  dim3 gd1((PR + 63)/64, Ff/64);
  gemm_k<<<gd1, 256, 0, stream>>>(mhb, dec_ff1_w, dec_ff1_b, nullptr, ffh2, PR, Ff, Ee, 1);
  dim3 gd2((PR + 63)/64, Ee/64);
  gemm_k<<<gd2, 256, 0, stream>>>(ffh2, dec_ff2_w, dec_ff2_b, mhb, qrefb, PR, Ee, Ff, 0);
  score_k<<<PR, 128, 0, stream>>>(qrefb, xb, scoreb);
  final_k<<<PR, 512, 0, stream>>>(scoreb, cur_dist, ninf, (float*)d_out);
}

// Round 10
// 958.697 us; speedup vs baseline: 1.4501x; 1.0102x over previous
//
#include <hip/hip_runtime.h>
#include <math.h>

#define Bb 16
#define Nn 500
#define NT 501
#define Pp 100
#define Ee 128
#define Hh 8
#define Dd 16
#define Ff 512
#define Ll 6
#define Mtok (Bb*NT)   // 8016
#define PR (Bb*Pp)     // 1600
#define TJ 32          // attn_enc KV tile rows
#define SPLIT 4        // encoder KV-split (126,126,126,123)
#define KSEG 126
#define DSPLIT 4       // decoder KV-split
#define DSEG 126
#define ENCP (6*128*384)
#define DECP (128*256)

// ---------------------------------------------------------------- weight packing
__global__ __launch_bounds__(256) void pack_k(
    const float* __restrict__ ewq, const float* __restrict__ ewk, const float* __restrict__ ewv,
    const float* __restrict__ dwk, const float* __restrict__ dwv,
    float* __restrict__ encP, float* __restrict__ decP)
{
  int i = blockIdx.x*256 + threadIdx.x;
  if (i < ENCP) {
    int l = i / (128*384); int rem = i - l*128*384; int k = rem / 384; int n = rem - k*384;
    float v;
    if (n < 128)      v = ewq[((size_t)l*128 + k)*128 + n];
    else if (n < 256) v = ewk[((size_t)l*128 + k)*128 + (n-128)];
    else              v = ewv[((size_t)l*128 + k)*128 + (n-256)];
    encP[i] = v;
  } else {
    int j = i - ENCP;
    if (j < DECP) {
      int k = j >> 8; int n = j & 255;
      decP[j] = (n < 128) ? dwk[k*128 + n] : dwv[k*128 + (n-128)];
    }
  }
}

// ---------------------------------------------------------------- embed
__global__ __launch_bounds__(256) void embed_k(
    const float* __restrict__ depot_xy, const float* __restrict__ node_xy,
    const float* __restrict__ node_demand,
    const float* __restrict__ wD, const float* __restrict__ bD,
    const float* __restrict__ wN, const float* __restrict__ bN,
    float* __restrict__ x)
{
  int t = blockIdx.x*256 + threadIdx.x;
  if (t >= Mtok*Ee) return;
  int e   = t & (Ee-1);
  int tok = t >> 7;
  int b   = tok / NT;
  int n   = tok - b*NT;
  float v;
  if (n == 0) {
    v = depot_xy[b*2+0]*wD[0*Ee+e] + depot_xy[b*2+1]*wD[1*Ee+e] + bD[e];
  } else {
    int nn = n - 1;
    float c0 = node_xy[(b*Nn + nn)*2 + 0];
    float c1 = node_xy[(b*Nn + nn)*2 + 1];
    float c2 = node_demand[b*Nn + nn];
    v = c0*wN[0*Ee+e] + c1*wN[1*Ee+e] + c2*wN[2*Ee+e] + bN[e];
  }
  x[(size_t)tok*Ee + e] = v;
}

// ---------------------------------------------------------------- GEMM
// C[M,N] = A[M,K] @ W[K,N]  (+bias)(relu)(+res).  N%64==0, K%16==0.
// Double-buffered LDS (1 barrier/K-step); rows padded to 68 floats to break
// the 4-way bank conflict on the transposed As store (lanes share ar, ak*68
// spreads banks; 68*4B keeps rows 16B-aligned).
__global__ __launch_bounds__(256) void gemm_k(
    const float* __restrict__ A, const float* __restrict__ W,
    const float* __restrict__ bias, const float* __restrict__ res,
    float* __restrict__ C, int M, int N, int K, int relu)
{
  __shared__ __align__(16) float As[2][16][68];
  __shared__ __align__(16) float Bs[2][16][68];
  int tid = threadIdx.x;
  int tx = tid & 15, ty = tid >> 4;
  int m0 = blockIdx.x * 64, n0 = blockIdx.y * 64;
  float acc[4][4];
  #pragma unroll
  for (int i=0;i<4;i++)
    #pragma unroll
    for (int j=0;j<4;j++) acc[i][j] = 0.f;

  int ar = tid >> 2;
  int ak = (tid & 3) << 2;
  int br = tid >> 4;
  int bc = (tid & 15) << 2;

  const float* Ap = A + (size_t)(m0 + ar)*K + ak;
  const float* Wp = W + (size_t)br*N + n0 + bc;
  bool aok = (m0 + ar) < M;

  float4 av = aok ? *(const float4*)(Ap) : make_float4(0.f,0.f,0.f,0.f);
  float4 wv = *(const float4*)(Wp);

  int nk = K >> 4;
  for (int t = 0; t < nk; ++t) {
    int cur = t & 1;
    As[cur][ak+0][ar] = av.x; As[cur][ak+1][ar] = av.y;
    As[cur][ak+2][ar] = av.z; As[cur][ak+3][ar] = av.w;
    *(float4*)(&Bs[cur][br][bc]) = wv;
    __syncthreads();
    if (t+1 < nk) {
      av = aok ? *(const float4*)(Ap + (t+1)*16) : make_float4(0.f,0.f,0.f,0.f);
      wv = *(const float4*)(Wp + (size_t)(t+1)*16*N);
    }
    #pragma unroll
    for (int k=0;k<16;k++){
      float4 a4 = *(const float4*)(&As[cur][k][ty*4]);
      float4 b4 = *(const float4*)(&Bs[cur][k][tx*4]);
      float avv[4] = {a4.x,a4.y,a4.z,a4.w};
      float bvv[4] = {b4.x,b4.y,b4.z,b4.w};
      #pragma unroll
      for (int i=0;i<4;i++)
        #pragma unroll
        for (int j=0;j<4;j++)
          acc[i][j] = fmaf(avv[i], bvv[j], acc[i][j]);
    }
  }

  float4 bv = make_float4(0.f,0.f,0.f,0.f);
  if (bias) bv = *(const float4*)(bias + n0 + tx*4);
  #pragma unroll
  for (int i=0;i<4;i++){
    int row = m0 + ty*4 + i;
    if (row >= M) continue;
    float4 o;
    o.x = acc[i][0] + bv.x; o.y = acc[i][1] + bv.y;
    o.z = acc[i][2] + bv.z; o.w = acc[i][3] + bv.w;
    if (relu){ o.x=fmaxf(o.x,0.f); o.y=fmaxf(o.y,0.f); o.z=fmaxf(o.z,0.f); o.w=fmaxf(o.w,0.f); }
    if (res){
      float4 rv = *(const float4*)(res + (size_t)row*N + n0 + tx*4);
      o.x += rv.x; o.y += rv.y; o.z += rv.z; o.w += rv.w;
    }
    *(float4*)(C + (size_t)row*N + n0 + tx*4) = o;
  }
}

// ---------------------------------------------------------------- attention
__device__ __forceinline__ float dot4(float4 a, float4 b){
  return fmaf(a.x,b.x, fmaf(a.y,b.y, fmaf(a.z,b.z, a.w*b.w)));
}

// encoder self-attention, KV-split, NO max-tracking (scores provably tiny;
// o/l invariant to max shift). Writes unnormalized o + l per (s,bh,query).
__global__ __launch_bounds__(256) void attn_enc_k(
    const float* __restrict__ QKV, float* __restrict__ part_o,
    float* __restrict__ part_l)
{
  int blk = blockIdx.x;
  int s  = blk % SPLIT;
  int cc = blk / SPLIT;
  int c  = cc & 1;
  int bh = cc >> 1;
  int h  = bh & (Hh-1);
  int b  = bh >> 3;
  int p  = c*256 + (int)threadIdx.x;
  const int klo = s*KSEG;
  int kseg = NT - klo; if (kseg > KSEG) kseg = KSEG;   // 126,126,126,123

  __shared__ __align__(16) float4 Ks[2][TJ][4];
  __shared__ __align__(16) float4 Vs[2][TJ][4];

  int tid = threadIdx.x;
  int row = (tid >> 2) & 31;
  int lc  = tid & 3;
  bool isV = tid >= 128;
  const int kvoff = isV ? 256 : 128;

  float4 q0,q1,q2,q3;
  if (p < NT) {
    const float4* qp = (const float4*)(QKV + ((size_t)(b*NT + p))*384 + h*Dd);
    q0=qp[0]; q1=qp[1]; q2=qp[2]; q3=qp[3];
  } else {
    q0=q1=q2=q3=make_float4(0,0,0,0);
  }

  if (row < kseg) {
    float4 v = *((const float4*)(QKV + ((size_t)(b*NT + klo + row))*384 + kvoff + h*Dd) + lc);
    if (isV) Vs[0][row][lc] = v; else Ks[0][row][lc] = v;
  }
  __syncthreads();

  float l = 0.f;
  float4 o0=make_float4(0,0,0,0), o1=o0, o2=o0, o3=o0;
  const int ntiles = (kseg + TJ - 1)/TJ;
  int buf = 0;

  for (int t = 0; t < ntiles; ++t) {
    int j0 = t*TJ;
    if (t+1 < ntiles) {
      int jj = j0 + TJ + row;
      if (jj < kseg) {
        float4 v = *((const float4*)(QKV + ((size_t)(b*NT + klo + jj))*384 + kvoff + h*Dd) + lc);
        if (isV) Vs[buf^1][row][lc] = v; else Ks[buf^1][row][lc] = v;
      }
    }
    int jend = kseg - j0; if (jend > TJ) jend = TJ;

    if (p < NT) {
      #pragma unroll 4
      for (int jj=0;jj<jend;jj++){
        const float4* kr = &Ks[buf][jj][0];
        float s0 = (dot4(q0,kr[0])+dot4(q1,kr[1])) + (dot4(q2,kr[2])+dot4(q3,kr[3]));
        float w = __expf(s0 * 0.25f);
        l += w;
        const float4* vr = &Vs[buf][jj][0];
        float4 v0=vr[0],v1=vr[1],v2=vr[2],v3=vr[3];
        o0.x=fmaf(w,v0.x,o0.x); o0.y=fmaf(w,v0.y,o0.y); o0.z=fmaf(w,v0.z,o0.z); o0.w=fmaf(w,v0.w,o0.w);
        o1.x=fmaf(w,v1.x,o1.x); o1.y=fmaf(w,v1.y,o1.y); o1.z=fmaf(w,v1.z,o1.z); o1.w=fmaf(w,v1.w,o1.w);
        o2.x=fmaf(w,v2.x,o2.x); o2.y=fmaf(w,v2.y,o2.y); o2.z=fmaf(w,v2.z,o2.z); o2.w=fmaf(w,v2.w,o2.w);
        o3.x=fmaf(w,v3.x,o3.x); o3.y=fmaf(w,v3.y,o3.y); o3.z=fmaf(w,v3.z,o3.z); o3.w=fmaf(w,v3.w,o3.w);
      }
    }
    __syncthreads();
    buf ^= 1;
  }

  if (p < NT) {
    size_t rbase = ((size_t)s*128 + bh)*NT + p;
    float4* po = (float4*)(part_o + rbase*16);
    po[0]=o0; po[1]=o1; po[2]=o2; po[3]=o3;
    part_l[rbase] = l;
  }
}

// combine SPLIT partials (plain sums) -> O[b,q,h,d]
__global__ __launch_bounds__(256) void attn_comb_k(
    const float* __restrict__ part_o, const float* __restrict__ part_l,
    float* __restrict__ O)
{
  int t = blockIdx.x*256 + threadIdx.x;
  if (t >= 128*NT*16) return;
  int d  = t & 15;
  int rq = t >> 4;
  int q  = rq % NT;
  int bh = rq / NT;
  int h = bh & 7, b = bh >> 3;
  const size_t R = (size_t)128*NT;
  float L = 0.f, o = 0.f;
  #pragma unroll
  for (int s=0;s<SPLIT;s++){
    L += part_l[(size_t)s*R + rq];
    o += part_o[((size_t)s*R + rq)*16 + d];
  }
  O[((size_t)(b*NT + q))*Ee + h*Dd + d] = o / L;
}

// decoder cross-attention: LDS-staged broadcast + KV-split, no max-tracking.
__global__ __launch_bounds__(128) void attn_dec_k(
    const float* __restrict__ Q, const float* __restrict__ KV,
    const float* __restrict__ mask,
    float* __restrict__ part_o, float* __restrict__ part_l)
{
  int blk = blockIdx.x;
  int s  = blk & (DSPLIT-1);
  int bh = blk >> 2;
  int h  = bh & (Hh-1);
  int b  = bh >> 3;
  int klo = s*DSEG;
  int kn  = NT - klo; if (kn > DSEG) kn = DSEG;

  __shared__ __align__(16) float4 Ks[DSEG][4];
  __shared__ __align__(16) float4 Vs[DSEG][4];

  int tid = threadIdx.x;
  for (int i = tid; i < kn*8; i += 128) {
    int row  = i >> 3;
    int q8   = i & 7;
    int quad = q8 & 3;
    int isv  = q8 >> 2;
    float4 v = *(const float4*)(KV + ((size_t)(b*NT + klo + row))*256 + isv*128 + h*Dd + quad*4);
    if (isv) Vs[row][quad] = v; else Ks[row][quad] = v;
  }
  __syncthreads();

  int p = tid;
  if (p >= Pp) return;
  int r = b*Pp + p;
  const float4* qp = (const float4*)(Q + (size_t)r*Ee + h*Dd);
  float4 qa=qp[0], qb=qp[1], qc=qp[2], qd=qp[3];
  const float* mrow = mask + (size_t)r*NT + klo;

  float l = 0.f;
  float4 o0=make_float4(0,0,0,0), o1=o0, o2=o0, o3=o0;
  for (int j=0;j<kn;++j){
    float sc = (dot4(qa,Ks[j][0])+dot4(qb,Ks[j][1])) + (dot4(qc,Ks[j][2])+dot4(qd,Ks[j][3]));
    float w = __expf(sc*0.25f + mrow[j]);
    l += w;
    float4 v0=Vs[j][0],v1=Vs[j][1],v2=Vs[j][2],v3=Vs[j][3];
    o0.x=fmaf(w,v0.x,o0.x); o0.y=fmaf(w,v0.y,o0.y); o0.z=fmaf(w,v0.z,o0.z); o0.w=fmaf(w,v0.w,o0.w);
    o1.x=fmaf(w,v1.x,o1.x); o1.y=fmaf(w,v1.y,o1.y); o1.z=fmaf(w,v1.z,o1.z); o1.w=fmaf(w,v1.w,o1.w);
    o2.x=fmaf(w,v2.x,o2.x); o2.y=fmaf(w,v2.y,o2.y); o2.z=fmaf(w,v2.z,o2.z); o2.w=fmaf(w,v2.w,o2.w);
    o3.x=fmaf(w,v3.x,o3.x); o3.y=fmaf(w,v3.y,o3.y); o3.z=fmaf(w,v3.z,o3.z); o3.w=fmaf(w,v3.w,o3.w);
  }

  size_t rb = ((size_t)s*PR + r)*Hh + h;
  float4* po = (float4*)(part_o + rb*16);
  po[0]=o0; po[1]=o1; po[2]=o2; po[3]=o3;
  part_l[rb] = l;
}

// combine DSPLIT decoder partials (plain sums)
__global__ __launch_bounds__(256) void attn_dcomb_k(
    const float* __restrict__ part_o, const float* __restrict__ part_l,
    float* __restrict__ O)
{
  int t = blockIdx.x*256 + threadIdx.x;
  if (t >= PR*Ee) return;
  int d = t & 15;
  int h = (t >> 4) & 7;
  int r = t >> 7;
  const size_t S = (size_t)PR*Hh;
  size_t rb = (size_t)r*Hh + h;
  float L = 0.f, o = 0.f;
  #pragma unroll
  for (int s=0;s<DSPLIT;s++){
    L += part_l[(size_t)s*S + rb];
    o += part_o[((size_t)s*S + rb)*16 + d];
  }
  O[(size_t)r*Ee + h*Dd + d] = o / L;
}

// ---------------------------------------------------------------- decoder small ops
__global__ __launch_bounds__(256) void gather_k(
    const float* __restrict__ x, const int* __restrict__ cur, float* __restrict__ encl)
{
  int t = blockIdx.x*256 + threadIdx.x;
  if (t >= PR*Ee) return;
  int e = t & (Ee-1);
  int r = t >> 7;
  int b = r / Pp;
  int node = cur[r];
  encl[(size_t)r*Ee + e] = x[((size_t)(b*NT + node))*Ee + e];
}

__global__ __launch_bounds__(128) void decq_k(
    const float* __restrict__ encl, const float* __restrict__ loadv,
    const float* __restrict__ Wq, float* __restrict__ q)
{
  __shared__ float row[Ee];
  int r = blockIdx.x, e = threadIdx.x;
  row[e] = encl[(size_t)r*Ee + e];
  __syncthreads();
  float acc = 0.f;
  #pragma unroll 4
  for (int k=0;k<Ee;k++) acc = fmaf(row[k], Wq[k*128 + e], acc);
  acc = fmaf(loadv[r], Wq[Ee*128 + e], acc);
  q[(size_t)r*128 + e] = acc;
}

__global__ __launch_bounds__(128) void dec_comb_k(
    const float* __restrict__ att, const float* __restrict__ W,
    const float* __restrict__ bias, const float* __restrict__ encl,
    const float* __restrict__ loadv, const float* __restrict__ capw,
    float* __restrict__ mh)
{
  __shared__ float row[Ee];
  int r = blockIdx.x, e = threadIdx.x;
  row[e] = att[(size_t)r*Ee + e];
  __syncthreads();
  float acc = 0.f;
  #pragma unroll 4
  for (int k=0;k<Ee;k++) acc = fmaf(row[k], W[k*Ee + e], acc);
  mh[(size_t)r*Ee + e] = acc + bias[e] + encl[(size_t)r*Ee + e] + loadv[r]*capw[e];
}

// score[b,p,n] = dot(qref[b,p], x[b,n]) / sqrt(E)
// v2: half-wave (32 lanes) cooperatively reads one contiguous 512B row
// (perfect coalescing) + shfl-reduce; XCD-swizzled block mapping so the
// 100 blocks of one batch share a single XCD's L2 (x[b] fetched once/XCD).
__global__ __launch_bounds__(128) void score_k(
    const float* __restrict__ qref, const float* __restrict__ x, float* __restrict__ score)
{
  int bid = blockIdx.x;           // 1600 blocks
  int xcd = bid & 7;
  int idx = bid >> 3;             // 0..199
  int b   = xcd*2 + (idx >= Pp ? 1 : 0);
  int p   = (idx >= Pp) ? idx - Pp : idx;
  int r   = b*Pp + p;

  __shared__ __align__(16) float4 q4[32];
  int tid = threadIdx.x;
  if (tid < 32) q4[tid] = ((const float4*)(qref + (size_t)r*Ee))[tid];
  __syncthreads();

  const float4* xb4 = (const float4*)(x + ((size_t)b*NT)*Ee);
  int lane = tid & 63;
  int w    = tid >> 6;            // wave 0/1
  int sub  = lane >> 5;           // half-wave row selector
  int q32  = lane & 31;
  float4 qv = q4[q32];
  for (int base = 0; base < NT; base += 4) {
    int n = base + w*2 + sub;
    float s = 0.f;
    if (n < NT) {
      float4 xv = xb4[(size_t)n*32 + q32];
      s = dot4(qv, xv);
    }
    s += __shfl_xor(s, 1, 32);
    s += __shfl_xor(s, 2, 32);
    s += __shfl_xor(s, 4, 32);
    s += __shfl_xor(s, 8, 32);
    s += __shfl_xor(s, 16, 32);
    if (q32 == 0 && n < NT)
      score[(size_t)r*NT + n] = s * 0.08838834764831845f;  // 1/sqrt(128)
  }
}

// ---------------------------------------------------------------- threefry noise
__device__ __forceinline__ unsigned rotl32(unsigned x, int r){ return (x<<r)|(x>>(32-r)); }

__device__ float tf_normal(unsigned idx)
{
  unsigned x0 = 0u;
  unsigned x1 = idx;
  const unsigned ks[3] = {0u, 42u, 0u ^ 42u ^ 0x1BD11BDAu};
  x0 += ks[0]; x1 += ks[1];
  const int rotA[4] = {13,15,26,6};
  const int rotB[4] = {17,29,16,24};
  #pragma unroll
  for (int i=0;i<5;i++){
    #pragma unroll
    for (int q=0;q<4;q++){
      int rr = (i&1) ? rotB[q] : rotA[q];
      x0 += x1; x1 = rotl32(x1, rr); x1 ^= x0;
    }
    x0 += ks[(i+1)%3];
    x1 += ks[(i+2)%3] + (unsigned)(i+1);
  }
  unsigned bits = x0 ^ x1;
  float f = __uint_as_float((bits >> 9) | 0x3f800000u) - 1.0f;
  const float lo = -0.99999994f;
  float u = f * 2.0f + lo;
  u = fmaxf(lo, u);
  float w = -log1pf(-u*u);
  float p;
  if (w < 5.0f) {
    w -= 2.5f;
    p = 2.81022636e-08f;
    p = fmaf(p, w, 3.43273939e-07f);
    p = fmaf(p, w, -3.5233877e-06f);
    p = fmaf(p, w, -4.39150654e-06f);
    p = fmaf(p, w, 0.00021858087f);
    p = fmaf(p, w, -0.00125372503f);
    p = fmaf(p, w, -0.00417768164f);
    p = fmaf(p, w, 0.246640727f);
    p = fmaf(p, w, 1.50140941f);
  } else {
    w = sqrtf(w) - 3.0f;
    p = -0.000200214257f;
    p = fmaf(p, w, 0.000100950558f);
    p = fmaf(p, w, 0.00134934322f);
    p = fmaf(p, w, -0.00367342844f);
    p = fmaf(p, w, 0.00573950773f);
    p = fmaf(p, w, -0.0076224613f);
    p = fmaf(p, w, 0.00943887047f);
    p = fmaf(p, w, 1.00167406f);
    p = fmaf(p, w, 2.83297682f);
  }
  return 1.4142135623730951f * (p * u);
}

// ---------------------------------------------------------------- finalize (f32)
__global__ __launch_bounds__(512) void final_k(
    const float* __restrict__ score, const float* __restrict__ cur_dist,
    const float* __restrict__ ninf, float* __restrict__ out)
{
  __shared__ float red[512];
  const float NM = (float)(50.0/501.0);
  const float C1 = (float)(1.0 - 50.0/501.0);
  int r = blockIdx.x;
  int t = threadIdx.x;
  float cd = 0.f, dmn = 1e30f, dmx = -1e30f;
  if (t < NT) { cd = cur_dist[(size_t)r*NT + t]; dmn = cd; dmx = cd; }
  red[t] = dmn; __syncthreads();
  for (int s=256;s>0;s>>=1){ if (t<s) red[t]=fminf(red[t],red[t+s]); __syncthreads(); }
  float dmin = red[0]; __syncthreads();
  red[t] = dmx; __syncthreads();
  for (int s=256;s>0;s>>=1){ if (t<s) red[t]=fmaxf(red[t],red[t+s]); __syncthreads(); }
  float dmax = red[0]; __syncthreads();

  float sval = -1e30f;
  if (t < NT) {
    float nd = (cd - dmin) / (dmax - dmin + 1e-6f);
    float z  = tf_normal((unsigned)r*501u + (unsigned)t);
    float s  = score[(size_t)r*NT + t] - C1*logf(nd + 1e-6f) + (z*0.2f + 0.5f)*NM;
    sval = 10.0f*tanhf(s) + ninf[(size_t)r*NT + t];
  }
  red[t] = sval; __syncthreads();
  for (int s=256;s>0;s>>=1){ if (t<s) red[t]=fmaxf(red[t],red[t+s]); __syncthreads(); }
  float smax = red[0]; __syncthreads();
  float e = (t < NT) ? expf(sval - smax) : 0.f;
  red[t] = e; __syncthreads();
  for (int s=256;s>0;s>>=1){ if (t<s) red[t]+=red[t+s]; __syncthreads(); }
  float ssum = red[0];
  if (t < NT) out[(size_t)r*NT + t] = e / ssum;
}

// ---------------------------------------------------------------- launch
extern "C" void kernel_launch(void* const* d_in, const int* in_sizes, int n_in,
                              void* d_out, int out_size, void* d_ws, size_t ws_size,
                              hipStream_t stream)
{
  (void)in_sizes; (void)n_in; (void)out_size; (void)ws_size;
  const float* depot_xy    = (const float*)d_in[0];
  const float* node_xy     = (const float*)d_in[1];
  const float* node_demand = (const float*)d_in[2];
  const float* loadv       = (const float*)d_in[3];
  const float* cur_dist    = (const float*)d_in[4];
  const float* ninf        = (const float*)d_in[5];
  const int*   cur_node    = (const int*)d_in[6];
  const float* emb_depot_w = (const float*)d_in[7];
  const float* emb_depot_b = (const float*)d_in[8];
  const float* emb_node_w  = (const float*)d_in[9];
  const float* emb_node_b  = (const float*)d_in[10];
  const float* enc_wq      = (const float*)d_in[11];
  const float* enc_wk      = (const float*)d_in[12];
  const float* enc_wv      = (const float*)d_in[13];
  const float* enc_comb_w  = (const float*)d_in[14];
  const float* enc_comb_b  = (const float*)d_in[15];
  const float* enc_ff1_w   = (const float*)d_in[16];
  const float* enc_ff1_b   = (const float*)d_in[17];
  const float* enc_ff2_w   = (const float*)d_in[18];
  const float* enc_ff2_b   = (const float*)d_in[19];
  const float* dec_wq_last = (const float*)d_in[20];
  const float* dec_wk      = (const float*)d_in[21];
  const float* dec_wv      = (const float*)d_in[22];
  const float* dec_comb_w  = (const float*)d_in[23];
  const float* dec_comb_b  = (const float*)d_in[24];
  const float* dec_cap_w   = (const float*)d_in[25];
  const float* dec_ff1_w   = (const float*)d_in[26];
  const float* dec_ff1_b   = (const float*)d_in[27];
  const float* dec_ff2_w   = (const float*)d_in[28];
  const float* dec_ff2_b   = (const float*)d_in[29];

  float* ws = (float*)d_ws;
  const size_t SZ = (size_t)Mtok*Ee;   // 1,026,048
  float* xb    = ws + 0*SZ;
  float* qkvb  = ws + 1*SZ;            // enc QKV [Mtok][384]; dec KV [Mtok][256]
  float* atb   = ws + 4*SZ;
  float* o1b   = ws + 5*SZ;
  float* ffb   = ws + 6*SZ;            // FF scratch (4*SZ)
  float* encPk = ws + 10*SZ;
  float* decPk = encPk + ENCP;
  float* part_o = ffb;
  float* part_l = o1b;
  float* dpart_o = ffb;
  float* dpart_l = o1b;
  float* encl  = qkvb + 2*SZ;
  float* qdec  = encl + 204800;
  float* attd  = qdec + 204800;
  float* mhb   = attd + 204800;
  float* qrefb = atb;
  float* ffh2  = ffb;
  float* scoreb= o1b;

  pack_k<<<(ENCP + DECP + 255)/256, 256, 0, stream>>>(
      enc_wq, enc_wk, enc_wv, dec_wk, dec_wv, encPk, decPk);

  embed_k<<<(Mtok*Ee + 255)/256, 256, 0, stream>>>(
      depot_xy, node_xy, node_demand, emb_depot_w, emb_depot_b,
      emb_node_w, emb_node_b, xb);

  dim3 gqkv((Mtok + 63)/64, 384/64);
  dim3 g128((Mtok + 63)/64, Ee/64);
  dim3 gff ((Mtok + 63)/64, Ff/64);
  const int gcomb = (128*NT*16 + 255)/256;
  for (int l = 0; l < Ll; ++l) {
    gemm_k<<<gqkv, 256, 0, stream>>>(xb, encPk + (size_t)l*128*384, nullptr, nullptr, qkvb, Mtok, 384, Ee, 0);
    attn_enc_k<<<Bb*Hh*2*SPLIT, 256, 0, stream>>>(qkvb, part_o, part_l);
    attn_comb_k<<<gcomb, 256, 0, stream>>>(part_o, part_l, atb);
    gemm_k<<<g128, 256, 0, stream>>>(atb, enc_comb_w + (size_t)l*Ee*Ee, enc_comb_b + l*Ee, xb, o1b, Mtok, Ee, Ee, 0);
    gemm_k<<<gff, 256, 0, stream>>>(o1b, enc_ff1_w + (size_t)l*Ee*Ff, enc_ff1_b + l*Ff, nullptr, ffb, Mtok, Ff, Ee, 1);
    gemm_k<<<g128, 256, 0, stream>>>(ffb, enc_ff2_w + (size_t)l*Ff*Ee, enc_ff2_b + l*Ee, o1b, xb, Mtok, Ee, Ff, 0);
  }

  // decoder
  dim3 gkv((Mtok + 63)/64, 256/64);
  gemm_k<<<gkv, 256, 0, stream>>>(xb, decPk, nullptr, nullptr, qkvb, Mtok, 256, Ee, 0);
  gather_k<<<(PR*Ee + 255)/256, 256, 0, stream>>>(xb, cur_node, encl);
  decq_k<<<PR, 128, 0, stream>>>(encl, loadv, dec_wq_last, qdec);
  attn_dec_k<<<Bb*Hh*DSPLIT, 128, 0, stream>>>(qdec, qkvb, ninf, dpart_o, dpart_l);
  attn_dcomb_k<<<(PR*Ee + 255)/256, 256, 0, stream>>>(dpart_o, dpart_l, attd);
  dec_comb_k<<<PR, 128, 0, stream>>>(attd, dec_comb_w, dec_comb_b, encl, loadv, dec_cap_w, mhb);
  dim3 gd1((PR + 63)/64, Ff/64);
  gemm_k<<<gd1, 256, 0, stream>>>(mhb, dec_ff1_w, dec_ff1_b, nullptr, ffh2, PR, Ff, Ee, 1);
  dim3 gd2((PR + 63)/64, Ee/64);
  gemm_k<<<gd2, 256, 0, stream>>>(ffh2, dec_ff2_w, dec_ff2_b, mhb, qrefb, PR, Ee, Ff, 0);
  score_k<<<PR, 128, 0, stream>>>(qrefb, xb, scoreb);
  final_k<<<PR, 512, 0, stream>>>(scoreb, cur_dist, ninf, (float*)d_out);
}

// Round 11
// 909.481 us; speedup vs baseline: 1.5286x; 1.0541x over previous
//
#include <hip/hip_runtime.h>
#include <math.h>

#define Bb 16
#define Nn 500
#define NT 501
#define Pp 100
#define Ee 128
#define Hh 8
#define Dd 16
#define Ff 512
#define Ll 6
#define Mtok (Bb*NT)   // 8016
#define PR (Bb*Pp)     // 1600
#define TJ 32          // attn_enc KV tile rows
#define SPLIT 4        // encoder KV-split (126,126,126,123)
#define KSEG 126
#define DSPLIT 4       // decoder KV-split
#define DSEG 126
#define ENCP (6*128*384)
#define DECP (128*256)
#define SNP 512        // padded score row stride

// ---------------------------------------------------------------- weight packing
__global__ __launch_bounds__(256) void pack_k(
    const float* __restrict__ ewq, const float* __restrict__ ewk, const float* __restrict__ ewv,
    const float* __restrict__ dwk, const float* __restrict__ dwv,
    float* __restrict__ encP, float* __restrict__ decP)
{
  int i = blockIdx.x*256 + threadIdx.x;
  if (i < ENCP) {
    int l = i / (128*384); int rem = i - l*128*384; int k = rem / 384; int n = rem - k*384;
    float v;
    if (n < 128)      v = ewq[((size_t)l*128 + k)*128 + n];
    else if (n < 256) v = ewk[((size_t)l*128 + k)*128 + (n-128)];
    else              v = ewv[((size_t)l*128 + k)*128 + (n-256)];
    encP[i] = v;
  } else {
    int j = i - ENCP;
    if (j < DECP) {
      int k = j >> 8; int n = j & 255;
      decP[j] = (n < 128) ? dwk[k*128 + n] : dwv[k*128 + (n-128)];
    }
  }
}

// ---------------------------------------------------------------- embed
__global__ __launch_bounds__(256) void embed_k(
    const float* __restrict__ depot_xy, const float* __restrict__ node_xy,
    const float* __restrict__ node_demand,
    const float* __restrict__ wD, const float* __restrict__ bD,
    const float* __restrict__ wN, const float* __restrict__ bN,
    float* __restrict__ x)
{
  int t = blockIdx.x*256 + threadIdx.x;
  if (t >= Mtok*Ee) return;
  int e   = t & (Ee-1);
  int tok = t >> 7;
  int b   = tok / NT;
  int n   = tok - b*NT;
  float v;
  if (n == 0) {
    v = depot_xy[b*2+0]*wD[0*Ee+e] + depot_xy[b*2+1]*wD[1*Ee+e] + bD[e];
  } else {
    int nn = n - 1;
    float c0 = node_xy[(b*Nn + nn)*2 + 0];
    float c1 = node_xy[(b*Nn + nn)*2 + 1];
    float c2 = node_demand[b*Nn + nn];
    v = c0*wN[0*Ee+e] + c1*wN[1*Ee+e] + c2*wN[2*Ee+e] + bN[e];
  }
  x[(size_t)tok*Ee + e] = v;
}

// ---------------------------------------------------------------- GEMM
// C[M,N] = A[M,K] @ W[K,N]  (+bias)(relu)(+res).  N%64==0, K%16==0.
// Double-buffered LDS (1 barrier/K-step); rows padded to 68 floats.
__global__ __launch_bounds__(256) void gemm_k(
    const float* __restrict__ A, const float* __restrict__ W,
    const float* __restrict__ bias, const float* __restrict__ res,
    float* __restrict__ C, int M, int N, int K, int relu)
{
  __shared__ __align__(16) float As[2][16][68];
  __shared__ __align__(16) float Bs[2][16][68];
  int tid = threadIdx.x;
  int tx = tid & 15, ty = tid >> 4;
  int m0 = blockIdx.x * 64, n0 = blockIdx.y * 64;
  float acc[4][4];
  #pragma unroll
  for (int i=0;i<4;i++)
    #pragma unroll
    for (int j=0;j<4;j++) acc[i][j] = 0.f;

  int ar = tid >> 2;
  int ak = (tid & 3) << 2;
  int br = tid >> 4;
  int bc = (tid & 15) << 2;

  const float* Ap = A + (size_t)(m0 + ar)*K + ak;
  const float* Wp = W + (size_t)br*N + n0 + bc;
  bool aok = (m0 + ar) < M;

  float4 av = aok ? *(const float4*)(Ap) : make_float4(0.f,0.f,0.f,0.f);
  float4 wv = *(const float4*)(Wp);

  int nk = K >> 4;
  for (int t = 0; t < nk; ++t) {
    int cur = t & 1;
    As[cur][ak+0][ar] = av.x; As[cur][ak+1][ar] = av.y;
    As[cur][ak+2][ar] = av.z; As[cur][ak+3][ar] = av.w;
    *(float4*)(&Bs[cur][br][bc]) = wv;
    __syncthreads();
    if (t+1 < nk) {
      av = aok ? *(const float4*)(Ap + (t+1)*16) : make_float4(0.f,0.f,0.f,0.f);
      wv = *(const float4*)(Wp + (size_t)(t+1)*16*N);
    }
    #pragma unroll
    for (int k=0;k<16;k++){
      float4 a4 = *(const float4*)(&As[cur][k][ty*4]);
      float4 b4 = *(const float4*)(&Bs[cur][k][tx*4]);
      float avv[4] = {a4.x,a4.y,a4.z,a4.w};
      float bvv[4] = {b4.x,b4.y,b4.z,b4.w};
      #pragma unroll
      for (int i=0;i<4;i++)
        #pragma unroll
        for (int j=0;j<4;j++)
          acc[i][j] = fmaf(avv[i], bvv[j], acc[i][j]);
    }
  }

  float4 bv = make_float4(0.f,0.f,0.f,0.f);
  if (bias) bv = *(const float4*)(bias + n0 + tx*4);
  #pragma unroll
  for (int i=0;i<4;i++){
    int row = m0 + ty*4 + i;
    if (row >= M) continue;
    float4 o;
    o.x = acc[i][0] + bv.x; o.y = acc[i][1] + bv.y;
    o.z = acc[i][2] + bv.z; o.w = acc[i][3] + bv.w;
    if (relu){ o.x=fmaxf(o.x,0.f); o.y=fmaxf(o.y,0.f); o.z=fmaxf(o.z,0.f); o.w=fmaxf(o.w,0.f); }
    if (res){
      float4 rv = *(const float4*)(res + (size_t)row*N + n0 + tx*4);
      o.x += rv.x; o.y += rv.y; o.z += rv.z; o.w += rv.w;
    }
    *(float4*)(C + (size_t)row*N + n0 + tx*4) = o;
  }
}

// ---------------------------------------------------------------- attention
__device__ __forceinline__ float dot4(float4 a, float4 b){
  return fmaf(a.x,b.x, fmaf(a.y,b.y, fmaf(a.z,b.z, a.w*b.w)));
}

// encoder self-attention, KV-split, NO max-tracking (scores provably tiny).
__global__ __launch_bounds__(256) void attn_enc_k(
    const float* __restrict__ QKV, float* __restrict__ part_o,
    float* __restrict__ part_l)
{
  int blk = blockIdx.x;
  int s  = blk % SPLIT;
  int cc = blk / SPLIT;
  int c  = cc & 1;
  int bh = cc >> 1;
  int h  = bh & (Hh-1);
  int b  = bh >> 3;
  int p  = c*256 + (int)threadIdx.x;
  const int klo = s*KSEG;
  int kseg = NT - klo; if (kseg > KSEG) kseg = KSEG;   // 126,126,126,123

  __shared__ __align__(16) float4 Ks[2][TJ][4];
  __shared__ __align__(16) float4 Vs[2][TJ][4];

  int tid = threadIdx.x;
  int row = (tid >> 2) & 31;
  int lc  = tid & 3;
  bool isV = tid >= 128;
  const int kvoff = isV ? 256 : 128;

  float4 q0,q1,q2,q3;
  if (p < NT) {
    const float4* qp = (const float4*)(QKV + ((size_t)(b*NT + p))*384 + h*Dd);
    q0=qp[0]; q1=qp[1]; q2=qp[2]; q3=qp[3];
  } else {
    q0=q1=q2=q3=make_float4(0,0,0,0);
  }

  if (row < kseg) {
    float4 v = *((const float4*)(QKV + ((size_t)(b*NT + klo + row))*384 + kvoff + h*Dd) + lc);
    if (isV) Vs[0][row][lc] = v; else Ks[0][row][lc] = v;
  }
  __syncthreads();

  float l = 0.f;
  float4 o0=make_float4(0,0,0,0), o1=o0, o2=o0, o3=o0;
  const int ntiles = (kseg + TJ - 1)/TJ;
  int buf = 0;

  for (int t = 0; t < ntiles; ++t) {
    int j0 = t*TJ;
    if (t+1 < ntiles) {
      int jj = j0 + TJ + row;
      if (jj < kseg) {
        float4 v = *((const float4*)(QKV + ((size_t)(b*NT + klo + jj))*384 + kvoff + h*Dd) + lc);
        if (isV) Vs[buf^1][row][lc] = v; else Ks[buf^1][row][lc] = v;
      }
    }
    int jend = kseg - j0; if (jend > TJ) jend = TJ;

    if (p < NT) {
      #pragma unroll 4
      for (int jj=0;jj<jend;jj++){
        const float4* kr = &Ks[buf][jj][0];
        float s0 = (dot4(q0,kr[0])+dot4(q1,kr[1])) + (dot4(q2,kr[2])+dot4(q3,kr[3]));
        float w = __expf(s0 * 0.25f);
        l += w;
        const float4* vr = &Vs[buf][jj][0];
        float4 v0=vr[0],v1=vr[1],v2=vr[2],v3=vr[3];
        o0.x=fmaf(w,v0.x,o0.x); o0.y=fmaf(w,v0.y,o0.y); o0.z=fmaf(w,v0.z,o0.z); o0.w=fmaf(w,v0.w,o0.w);
        o1.x=fmaf(w,v1.x,o1.x); o1.y=fmaf(w,v1.y,o1.y); o1.z=fmaf(w,v1.z,o1.z); o1.w=fmaf(w,v1.w,o1.w);
        o2.x=fmaf(w,v2.x,o2.x); o2.y=fmaf(w,v2.y,o2.y); o2.z=fmaf(w,v2.z,o2.z); o2.w=fmaf(w,v2.w,o2.w);
        o3.x=fmaf(w,v3.x,o3.x); o3.y=fmaf(w,v3.y,o3.y); o3.z=fmaf(w,v3.z,o3.z); o3.w=fmaf(w,v3.w,o3.w);
      }
    }
    __syncthreads();
    buf ^= 1;
  }

  if (p < NT) {
    size_t rbase = ((size_t)s*128 + bh)*NT + p;
    float4* po = (float4*)(part_o + rbase*16);
    po[0]=o0; po[1]=o1; po[2]=o2; po[3]=o3;
    part_l[rbase] = l;
  }
}

// combine SPLIT partials (plain sums) -> O[b,q,h,d]
__global__ __launch_bounds__(256) void attn_comb_k(
    const float* __restrict__ part_o, const float* __restrict__ part_l,
    float* __restrict__ O)
{
  int t = blockIdx.x*256 + threadIdx.x;
  if (t >= 128*NT*16) return;
  int d  = t & 15;
  int rq = t >> 4;
  int q  = rq % NT;
  int bh = rq / NT;
  int h = bh & 7, b = bh >> 3;
  const size_t R = (size_t)128*NT;
  float L = 0.f, o = 0.f;
  #pragma unroll
  for (int s=0;s<SPLIT;s++){
    L += part_l[(size_t)s*R + rq];
    o += part_o[((size_t)s*R + rq)*16 + d];
  }
  O[((size_t)(b*NT + q))*Ee + h*Dd + d] = o / L;
}

// decoder cross-attention: LDS-staged broadcast + KV-split, no max-tracking.
__global__ __launch_bounds__(128) void attn_dec_k(
    const float* __restrict__ Q, const float* __restrict__ KV,
    const float* __restrict__ mask,
    float* __restrict__ part_o, float* __restrict__ part_l)
{
  int blk = blockIdx.x;
  int s  = blk & (DSPLIT-1);
  int bh = blk >> 2;
  int h  = bh & (Hh-1);
  int b  = bh >> 3;
  int klo = s*DSEG;
  int kn  = NT - klo; if (kn > DSEG) kn = DSEG;

  __shared__ __align__(16) float4 Ks[DSEG][4];
  __shared__ __align__(16) float4 Vs[DSEG][4];

  int tid = threadIdx.x;
  for (int i = tid; i < kn*8; i += 128) {
    int row  = i >> 3;
    int q8   = i & 7;
    int quad = q8 & 3;
    int isv  = q8 >> 2;
    float4 v = *(const float4*)(KV + ((size_t)(b*NT + klo + row))*256 + isv*128 + h*Dd + quad*4);
    if (isv) Vs[row][quad] = v; else Ks[row][quad] = v;
  }
  __syncthreads();

  int p = tid;
  if (p >= Pp) return;
  int r = b*Pp + p;
  const float4* qp = (const float4*)(Q + (size_t)r*Ee + h*Dd);
  float4 qa=qp[0], qb=qp[1], qc=qp[2], qd=qp[3];
  const float* mrow = mask + (size_t)r*NT + klo;

  float l = 0.f;
  float4 o0=make_float4(0,0,0,0), o1=o0, o2=o0, o3=o0;
  for (int j=0;j<kn;++j){
    float sc = (dot4(qa,Ks[j][0])+dot4(qb,Ks[j][1])) + (dot4(qc,Ks[j][2])+dot4(qd,Ks[j][3]));
    float w = __expf(sc*0.25f + mrow[j]);
    l += w;
    float4 v0=Vs[j][0],v1=Vs[j][1],v2=Vs[j][2],v3=Vs[j][3];
    o0.x=fmaf(w,v0.x,o0.x); o0.y=fmaf(w,v0.y,o0.y); o0.z=fmaf(w,v0.z,o0.z); o0.w=fmaf(w,v0.w,o0.w);
    o1.x=fmaf(w,v1.x,o1.x); o1.y=fmaf(w,v1.y,o1.y); o1.z=fmaf(w,v1.z,o1.z); o1.w=fmaf(w,v1.w,o1.w);
    o2.x=fmaf(w,v2.x,o2.x); o2.y=fmaf(w,v2.y,o2.y); o2.z=fmaf(w,v2.z,o2.z); o2.w=fmaf(w,v2.w,o2.w);
    o3.x=fmaf(w,v3.x,o3.x); o3.y=fmaf(w,v3.y,o3.y); o3.z=fmaf(w,v3.z,o3.z); o3.w=fmaf(w,v3.w,o3.w);
  }

  size_t rb = ((size_t)s*PR + r)*Hh + h;
  float4* po = (float4*)(part_o + rb*16);
  po[0]=o0; po[1]=o1; po[2]=o2; po[3]=o3;
  part_l[rb] = l;
}

// combine DSPLIT decoder partials (plain sums)
__global__ __launch_bounds__(256) void attn_dcomb_k(
    const float* __restrict__ part_o, const float* __restrict__ part_l,
    float* __restrict__ O)
{
  int t = blockIdx.x*256 + threadIdx.x;
  if (t >= PR*Ee) return;
  int d = t & 15;
  int h = (t >> 4) & 7;
  int r = t >> 7;
  const size_t S = (size_t)PR*Hh;
  size_t rb = (size_t)r*Hh + h;
  float L = 0.f, o = 0.f;
  #pragma unroll
  for (int s=0;s<DSPLIT;s++){
    L += part_l[(size_t)s*S + rb];
    o += part_o[((size_t)s*S + rb)*16 + d];
  }
  O[(size_t)r*Ee + h*Dd + d] = o / L;
}

// ---------------------------------------------------------------- decoder small ops
__global__ __launch_bounds__(256) void gather_k(
    const float* __restrict__ x, const int* __restrict__ cur, float* __restrict__ encl)
{
  int t = blockIdx.x*256 + threadIdx.x;
  if (t >= PR*Ee) return;
  int e = t & (Ee-1);
  int r = t >> 7;
  int b = r / Pp;
  int node = cur[r];
  encl[(size_t)r*Ee + e] = x[((size_t)(b*NT + node))*Ee + e];
}

__global__ __launch_bounds__(128) void decq_k(
    const float* __restrict__ encl, const float* __restrict__ loadv,
    const float* __restrict__ Wq, float* __restrict__ q)
{
  __shared__ float row[Ee];
  int r = blockIdx.x, e = threadIdx.x;
  row[e] = encl[(size_t)r*Ee + e];
  __syncthreads();
  float acc = 0.f;
  #pragma unroll 4
  for (int k=0;k<Ee;k++) acc = fmaf(row[k], Wq[k*128 + e], acc);
  acc = fmaf(loadv[r], Wq[Ee*128 + e], acc);
  q[(size_t)r*128 + e] = acc;
}

__global__ __launch_bounds__(128) void dec_comb_k(
    const float* __restrict__ att, const float* __restrict__ W,
    const float* __restrict__ bias, const float* __restrict__ encl,
    const float* __restrict__ loadv, const float* __restrict__ capw,
    float* __restrict__ mh)
{
  __shared__ float row[Ee];
  int r = blockIdx.x, e = threadIdx.x;
  row[e] = att[(size_t)r*Ee + e];
  __syncthreads();
  float acc = 0.f;
  #pragma unroll 4
  for (int k=0;k<Ee;k++) acc = fmaf(row[k], W[k*Ee + e], acc);
  mh[(size_t)r*Ee + e] = acc + bias[e] + encl[(size_t)r*Ee + e] + loadv[r]*capw[e];
}

// ---------------------------------------------------------------- score via batched GEMM
// xT[b][k][n_pad] = x[b*NT+n][k] * (1/sqrt(128)), zero-padded n>=501.
// 32x32 LDS tile transpose, coalesced both sides.
__global__ __launch_bounds__(256) void xt_k(
    const float* __restrict__ x, float* __restrict__ xT)
{
  __shared__ float T[32][33];
  int n0 = blockIdx.x * 32;       // 0..480 (16 tiles, covers pad to 511)
  int k0 = blockIdx.y * 32;       // 0,32,64,96
  int b  = blockIdx.z;
  int t  = threadIdx.x;
  int row = t >> 3;               // 0..31
  int c4  = (t & 7) << 2;         // 0,4,..,28

  int n = n0 + row;
  float4 v = make_float4(0.f,0.f,0.f,0.f);
  if (n < NT) v = *(const float4*)(x + ((size_t)(b*NT + n))*Ee + k0 + c4);
  T[c4+0][row] = v.x; T[c4+1][row] = v.y; T[c4+2][row] = v.z; T[c4+3][row] = v.w;
  __syncthreads();

  const float SC = 0.08838834764831845f;
  float4 o;
  o.x = T[row][c4+0]*SC; o.y = T[row][c4+1]*SC;
  o.z = T[row][c4+2]*SC; o.w = T[row][c4+3]*SC;
  *(float4*)(xT + ((size_t)(b*Ee + k0 + row))*SNP + n0 + c4) = o;
}

// score[b][p][n_pad] = qref[b*100+p] @ xT[b]   (M=100, N=512, K=128)
__global__ __launch_bounds__(256) void score_gemm_k(
    const float* __restrict__ qref, const float* __restrict__ xT,
    float* __restrict__ score)
{
  __shared__ __align__(16) float As[2][16][68];
  __shared__ __align__(16) float Bs[2][16][68];
  int tid = threadIdx.x;
  int tx = tid & 15, ty = tid >> 4;
  int m0 = blockIdx.x * 64;       // 0,64
  int n0 = blockIdx.y * 64;       // 0..448
  int b  = blockIdx.z;

  const float* A = qref + (size_t)b*Pp*Ee;
  const float* W = xT   + (size_t)b*Ee*SNP;
  float*       C = score + (size_t)b*Pp*SNP;

  float acc[4][4];
  #pragma unroll
  for (int i=0;i<4;i++)
    #pragma unroll
    for (int j=0;j<4;j++) acc[i][j] = 0.f;

  int ar = tid >> 2;
  int ak = (tid & 3) << 2;
  int br = tid >> 4;
  int bc = (tid & 15) << 2;

  const float* Ap = A + (size_t)(m0 + ar)*Ee + ak;
  const float* Wp = W + (size_t)br*SNP + n0 + bc;
  bool aok = (m0 + ar) < Pp;

  float4 av = aok ? *(const float4*)(Ap) : make_float4(0.f,0.f,0.f,0.f);
  float4 wv = *(const float4*)(Wp);

  for (int t = 0; t < 8; ++t) {    // K=128
    int cur = t & 1;
    As[cur][ak+0][ar] = av.x; As[cur][ak+1][ar] = av.y;
    As[cur][ak+2][ar] = av.z; As[cur][ak+3][ar] = av.w;
    *(float4*)(&Bs[cur][br][bc]) = wv;
    __syncthreads();
    if (t+1 < 8) {
      av = aok ? *(const float4*)(Ap + (t+1)*16) : make_float4(0.f,0.f,0.f,0.f);
      wv = *(const float4*)(Wp + (size_t)(t+1)*16*SNP);
    }
    #pragma unroll
    for (int k=0;k<16;k++){
      float4 a4 = *(const float4*)(&As[cur][k][ty*4]);
      float4 b4 = *(const float4*)(&Bs[cur][k][tx*4]);
      float avv[4] = {a4.x,a4.y,a4.z,a4.w};
      float bvv[4] = {b4.x,b4.y,b4.z,b4.w};
      #pragma unroll
      for (int i=0;i<4;i++)
        #pragma unroll
        for (int j=0;j<4;j++)
          acc[i][j] = fmaf(avv[i], bvv[j], acc[i][j]);
    }
    __syncthreads();
  }

  #pragma unroll
  for (int i=0;i<4;i++){
    int row = m0 + ty*4 + i;
    if (row >= Pp) continue;
    float4 o;
    o.x = acc[i][0]; o.y = acc[i][1]; o.z = acc[i][2]; o.w = acc[i][3];
    *(float4*)(C + (size_t)row*SNP + n0 + tx*4) = o;
  }
}

// ---------------------------------------------------------------- threefry noise
__device__ __forceinline__ unsigned rotl32(unsigned x, int r){ return (x<<r)|(x>>(32-r)); }

__device__ float tf_normal(unsigned idx)
{
  unsigned x0 = 0u;
  unsigned x1 = idx;
  const unsigned ks[3] = {0u, 42u, 0u ^ 42u ^ 0x1BD11BDAu};
  x0 += ks[0]; x1 += ks[1];
  const int rotA[4] = {13,15,26,6};
  const int rotB[4] = {17,29,16,24};
  #pragma unroll
  for (int i=0;i<5;i++){
    #pragma unroll
    for (int q=0;q<4;q++){
      int rr = (i&1) ? rotB[q] : rotA[q];
      x0 += x1; x1 = rotl32(x1, rr); x1 ^= x0;
    }
    x0 += ks[(i+1)%3];
    x1 += ks[(i+2)%3] + (unsigned)(i+1);
  }
  unsigned bits = x0 ^ x1;
  float f = __uint_as_float((bits >> 9) | 0x3f800000u) - 1.0f;
  const float lo = -0.99999994f;
  float u = f * 2.0f + lo;
  u = fmaxf(lo, u);
  float w = -log1pf(-u*u);
  float p;
  if (w < 5.0f) {
    w -= 2.5f;
    p = 2.81022636e-08f;
    p = fmaf(p, w, 3.43273939e-07f);
    p = fmaf(p, w, -3.5233877e-06f);
    p = fmaf(p, w, -4.39150654e-06f);
    p = fmaf(p, w, 0.00021858087f);
    p = fmaf(p, w, -0.00125372503f);
    p = fmaf(p, w, -0.00417768164f);
    p = fmaf(p, w, 0.246640727f);
    p = fmaf(p, w, 1.50140941f);
  } else {
    w = sqrtf(w) - 3.0f;
    p = -0.000200214257f;
    p = fmaf(p, w, 0.000100950558f);
    p = fmaf(p, w, 0.00134934322f);
    p = fmaf(p, w, -0.00367342844f);
    p = fmaf(p, w, 0.00573950773f);
    p = fmaf(p, w, -0.0076224613f);
    p = fmaf(p, w, 0.00943887047f);
    p = fmaf(p, w, 1.00167406f);
    p = fmaf(p, w, 2.83297682f);
  }
  return 1.4142135623730951f * (p * u);
}

// ---------------------------------------------------------------- finalize (f32)
// wave-shfl reductions (3 barriers total); reads padded score [r][512].
__global__ __launch_bounds__(512) void final_k(
    const float* __restrict__ score, const float* __restrict__ cur_dist,
    const float* __restrict__ ninf, float* __restrict__ out)
{
  __shared__ float smn[8], smx[8], sm2[8], ss[8];
  const float NM = (float)(50.0/501.0);
  const float C1 = (float)(1.0 - 50.0/501.0);
  int r = blockIdx.x;
  int t = threadIdx.x;
  int wid = t >> 6, lane = t & 63;

  float cd = 0.f;
  float mn = 1e30f, mx = -1e30f;
  if (t < NT) { cd = cur_dist[(size_t)r*NT + t]; mn = cd; mx = cd; }
  #pragma unroll
  for (int off=32; off>=1; off>>=1){
    mn = fminf(mn, __shfl_xor(mn, off));
    mx = fmaxf(mx, __shfl_xor(mx, off));
  }
  if (lane == 0){ smn[wid] = mn; smx[wid] = mx; }
  __syncthreads();
  float dmin = smn[0], dmax = smx[0];
  #pragma unroll
  for (int i=1;i<8;i++){ dmin = fminf(dmin, smn[i]); dmax = fmaxf(dmax, smx[i]); }

  float sval = -1e30f;
  if (t < NT) {
    float nd = (cd - dmin) / (dmax - dmin + 1e-6f);
    float z  = tf_normal((unsigned)r*501u + (unsigned)t);
    float s  = score[(size_t)r*SNP + t] - C1*logf(nd + 1e-6f) + (z*0.2f + 0.5f)*NM;
    sval = 10.0f*tanhf(s) + ninf[(size_t)r*NT + t];
  }
  float mv = sval;
  #pragma unroll
  for (int off=32; off>=1; off>>=1) mv = fmaxf(mv, __shfl_xor(mv, off));
  if (lane == 0) sm2[wid] = mv;
  __syncthreads();
  float smax = sm2[0];
  #pragma unroll
  for (int i=1;i<8;i++) smax = fmaxf(smax, sm2[i]);

  float e = (t < NT) ? expf(sval - smax) : 0.f;
  float sv = e;
  #pragma unroll
  for (int off=32; off>=1; off>>=1) sv += __shfl_xor(sv, off);
  if (lane == 0) ss[wid] = sv;
  __syncthreads();
  float ssum = ss[0];
  #pragma unroll
  for (int i=1;i<8;i++) ssum += ss[i];

  if (t < NT) out[(size_t)r*NT + t] = e / ssum;
}

// ---------------------------------------------------------------- launch
extern "C" void kernel_launch(void* const* d_in, const int* in_sizes, int n_in,
                              void* d_out, int out_size, void* d_ws, size_t ws_size,
                              hipStream_t stream)
{
  (void)in_sizes; (void)n_in; (void)out_size; (void)ws_size;
  const float* depot_xy    = (const float*)d_in[0];
  const float* node_xy     = (const float*)d_in[1];
  const float* node_demand = (const float*)d_in[2];
  const float* loadv       = (const float*)d_in[3];
  const float* cur_dist    = (const float*)d_in[4];
  const float* ninf        = (const float*)d_in[5];
  const int*   cur_node    = (const int*)d_in[6];
  const float* emb_depot_w = (const float*)d_in[7];
  const float* emb_depot_b = (const float*)d_in[8];
  const float* emb_node_w  = (const float*)d_in[9];
  const float* emb_node_b  = (const float*)d_in[10];
  const float* enc_wq      = (const float*)d_in[11];
  const float* enc_wk      = (const float*)d_in[12];
  const float* enc_wv      = (const float*)d_in[13];
  const float* enc_comb_w  = (const float*)d_in[14];
  const float* enc_comb_b  = (const float*)d_in[15];
  const float* enc_ff1_w   = (const float*)d_in[16];
  const float* enc_ff1_b   = (const float*)d_in[17];
  const float* enc_ff2_w   = (const float*)d_in[18];
  const float* enc_ff2_b   = (const float*)d_in[19];
  const float* dec_wq_last = (const float*)d_in[20];
  const float* dec_wk      = (const float*)d_in[21];
  const float* dec_wv      = (const float*)d_in[22];
  const float* dec_comb_w  = (const float*)d_in[23];
  const float* dec_comb_b  = (const float*)d_in[24];
  const float* dec_cap_w   = (const float*)d_in[25];
  const float* dec_ff1_w   = (const float*)d_in[26];
  const float* dec_ff1_b   = (const float*)d_in[27];
  const float* dec_ff2_w   = (const float*)d_in[28];
  const float* dec_ff2_b   = (const float*)d_in[29];

  float* ws = (float*)d_ws;
  const size_t SZ = (size_t)Mtok*Ee;   // 1,026,048
  float* xb    = ws + 0*SZ;
  float* qkvb  = ws + 1*SZ;            // enc QKV [Mtok][384]; dec KV [Mtok][256]
  float* atb   = ws + 4*SZ;
  float* o1b   = ws + 5*SZ;
  float* ffb   = ws + 6*SZ;            // FF scratch (4*SZ)
  float* encPk = ws + 10*SZ;
  float* decPk = encPk + ENCP;
  float* part_o = ffb;
  float* part_l = o1b;
  float* dpart_o = ffb;
  float* dpart_l = o1b;
  float* encl  = qkvb + 2*SZ;
  float* qdec  = encl + 204800;
  float* attd  = qdec + 204800;
  float* mhb   = attd + 204800;
  float* qrefb = atb;
  float* ffh2  = ffb;
  float* xTb   = ffb;                  // 16*128*512 = 1,048,576 < 4*SZ (after ffh2 consumed)
  float* scoreb= o1b;                  // [PR][512] = 819,200 < SZ

  pack_k<<<(ENCP + DECP + 255)/256, 256, 0, stream>>>(
      enc_wq, enc_wk, enc_wv, dec_wk, dec_wv, encPk, decPk);

  embed_k<<<(Mtok*Ee + 255)/256, 256, 0, stream>>>(
      depot_xy, node_xy, node_demand, emb_depot_w, emb_depot_b,
      emb_node_w, emb_node_b, xb);

  dim3 gqkv((Mtok + 63)/64, 384/64);
  dim3 g128((Mtok + 63)/64, Ee/64);
  dim3 gff ((Mtok + 63)/64, Ff/64);
  const int gcomb = (128*NT*16 + 255)/256;
  for (int l = 0; l < Ll; ++l) {
    gemm_k<<<gqkv, 256, 0, stream>>>(xb, encPk + (size_t)l*128*384, nullptr, nullptr, qkvb, Mtok, 384, Ee, 0);
    attn_enc_k<<<Bb*Hh*2*SPLIT, 256, 0, stream>>>(qkvb, part_o, part_l);
    attn_comb_k<<<gcomb, 256, 0, stream>>>(part_o, part_l, atb);
    gemm_k<<<g128, 256, 0, stream>>>(atb, enc_comb_w + (size_t)l*Ee*Ee, enc_comb_b + l*Ee, xb, o1b, Mtok, Ee, Ee, 0);
    gemm_k<<<gff, 256, 0, stream>>>(o1b, enc_ff1_w + (size_t)l*Ee*Ff, enc_ff1_b + l*Ff, nullptr, ffb, Mtok, Ff, Ee, 1);
    gemm_k<<<g128, 256, 0, stream>>>(ffb, enc_ff2_w + (size_t)l*Ff*Ee, enc_ff2_b + l*Ee, o1b, xb, Mtok, Ee, Ff, 0);
  }

  // decoder
  dim3 gkv((Mtok + 63)/64, 256/64);
  gemm_k<<<gkv, 256, 0, stream>>>(xb, decPk, nullptr, nullptr, qkvb, Mtok, 256, Ee, 0);
  gather_k<<<(PR*Ee + 255)/256, 256, 0, stream>>>(xb, cur_node, encl);
  decq_k<<<PR, 128, 0, stream>>>(encl, loadv, dec_wq_last, qdec);
  attn_dec_k<<<Bb*Hh*DSPLIT, 128, 0, stream>>>(qdec, qkvb, ninf, dpart_o, dpart_l);
  attn_dcomb_k<<<(PR*Ee + 255)/256, 256, 0, stream>>>(dpart_o, dpart_l, attd);
  dec_comb_k<<<PR, 128, 0, stream>>>(attd, dec_comb_w, dec_comb_b, encl, loadv, dec_cap_w, mhb);
  dim3 gd1((PR + 63)/64, Ff/64);
  gemm_k<<<gd1, 256, 0, stream>>>(mhb, dec_ff1_w, dec_ff1_b, nullptr, ffh2, PR, Ff, Ee, 1);
  dim3 gd2((PR + 63)/64, Ee/64);
  gemm_k<<<gd2, 256, 0, stream>>>(ffh2, dec_ff2_w, dec_ff2_b, mhb, qrefb, PR, Ee, Ff, 0);
  // score = batched GEMM over transposed x
  dim3 gxt(16, 4, 16);
  xt_k<<<gxt, 256, 0, stream>>>(xb, xTb);
  dim3 gsc(2, 8, 16);
  score_gemm_k<<<gsc, 256, 0, stream>>>(qrefb, xTb, scoreb);
  final_k<<<PR, 512, 0, stream>>>(scoreb, cur_dist, ninf, (float*)d_out);
}